// Round 10
// baseline (240.635 us; speedup 1.0000x reference)
//
#include <hip/hip_runtime.h>
#include <hip/hip_bf16.h>
#include <math.h>

// B=32,T=512 -> NTOK=16384 tokens; F=64; H=64; E=32
#define NTOK 16384

typedef __attribute__((ext_vector_type(8))) short short8;   // 8 bf16 (MFMA A/B)
typedef __attribute__((ext_vector_type(4))) float f32x4;    // MFMA acc

__device__ __forceinline__ unsigned pack_bf16(float a, float b) {
    union { __hip_bfloat162 h; unsigned u; } cv;
    cv.h = __float22bfloat162_rn(make_float2(a, b));
    return cv.u;
}
__device__ __forceinline__ float eluf(float z) {
    return z > 0.0f ? z : (__expf(z) - 1.0f);
}

// ---------------- prepass: fragment-major bf16 B images ----------------
// slot f (0..63): B = ew3[f] (rows k=h, cols n); slot 64: B = eb3 (rows e, cols n)
// image[f][idx] uint4, idx = c*256 + u*64 + lane:
//   elem j of lane's short8 = B[c*32 + (lane>>4)*8 + j][u*16 + (lane&15)]
__global__ __launch_bounds__(256)
void prepass(const float* __restrict__ ew3, const float* __restrict__ eb3,
             unsigned short* __restrict__ ws) {
    __shared__ float tile[64 * 65];
    const int bid = blockIdx.x, tid = threadIdx.x;
    const float* src = (bid < 64) ? (ew3 + (size_t)bid * 4096) : eb3;

    const int r = tid >> 2, c0 = (tid & 3) * 16;
    #pragma unroll
    for (int j = 0; j < 4; ++j) {
        float4 v = *(const float4*)(src + r * 64 + c0 + j * 4);
        tile[r * 65 + c0 + j * 4 + 0] = v.x;
        tile[r * 65 + c0 + j * 4 + 1] = v.y;
        tile[r * 65 + c0 + j * 4 + 2] = v.z;
        tile[r * 65 + c0 + j * 4 + 3] = v.w;
    }
    __syncthreads();

    uint4* dst = (uint4*)(ws + (size_t)bid * 4096);
    #pragma unroll
    for (int it = 0; it < 2; ++it) {
        const int idx = tid + it * 256;
        const int c = idx >> 8, u = (idx >> 6) & 3, l = idx & 63;
        const int m = l & 15, q = (l >> 4) & 3;
        const int rb = c * 32 + q * 8, col = u * 16 + m;
        unsigned pw[4];
        #pragma unroll
        for (int p = 0; p < 4; ++p)
            pw[p] = pack_bf16(tile[(rb + 2 * p) * 65 + col],
                              tile[(rb + 2 * p + 1) * 65 + col]);
        uint4 pk; pk.x = pw[0]; pk.y = pw[1]; pk.z = pw[2]; pk.w = pw[3];
        dst[idx] = pk;
    }
}

// ---------------- main kernel: 256 blocks x 512 thr (8 waves) ----------------
// block = 64 tokens; wave wv: f in [wv*8, wv*8+8), FOUR 16-token M-tiles x N=64.
// B loaded once per f and reused across 4 tiles -> per-CU B traffic halved vs R8,
// per-iter VALU (~900 cyc) >> L2 latency -> loads fully hidden at 2 waves/SIMD.
__global__ __launch_bounds__(512, 2)
void moe_main(const float* __restrict__ x,   const float* __restrict__ s,
              const float* __restrict__ fw1, const float* __restrict__ fb1,
              const float* __restrict__ fw2, const float* __restrict__ fb2,
              const float* __restrict__ fw3, const float* __restrict__ fb3,
              const float* __restrict__ ew1, const float* __restrict__ eb1,
              const float* __restrict__ ew3, const float* __restrict__ eb3,
              const unsigned short* __restrict__ img,
              float* __restrict__ out)
{
    // xls [0,17408) | wts [17408,34048) | scr [34048,68864):
    //   gating: egs [64][64] (16384 B)   epilogue: ped [8][1088] (34816 B)
    __shared__ __align__(16) char smem[68864];
    float* xls = (float*)smem;                  // [64][68]
    float* wts = (float*)(smem + 17408);        // [64][65]
    float* egs = (float*)(smem + 34048);        // [64][64] (gating only)
    float* ped = (float*)(smem + 34048);        // [8][1088] (epilogue only)

    const int tid = threadIdx.x;
    const int wv = tid >> 6, lane = tid & 63;
    const int m = tid & 15, quad = (tid >> 4) & 3;
    const int tokbase = blockIdx.x * 64;

    // ---- stage x tile: 64 rows x 16 float4 = 1024, 2 per thread ----
    #pragma unroll
    for (int i = 0; i < 2; ++i) {
        const int idx = tid + i * 512;
        const int t = idx >> 4, fq = (idx & 15) * 4;
        *(float4*)&xls[t * 68 + fq] =
            *(const float4*)(x + (size_t)(tokbase + t) * 64 + fq);
    }
    __syncthreads();

    // ---- gating: each wave -> softmax gates for its 8 tokens ----
    {
        const int t0w = wv * 8;
        const float* sw = s + (size_t)(tokbase + t0w) * 32;
        float g[8];
        const float b0 = fb1[lane] + fb2[lane];
        #pragma unroll
        for (int t = 0; t < 8; ++t) g[t] = b0;
        #pragma unroll 2
        for (int f = 0; f < 64; f += 4) {
            const float w0 = fw1[(f + 0) * 64 + lane];
            const float w1 = fw1[(f + 1) * 64 + lane];
            const float w2 = fw1[(f + 2) * 64 + lane];
            const float w3v = fw1[(f + 3) * 64 + lane];
            #pragma unroll
            for (int t = 0; t < 8; ++t) {
                const float4 xa = *(const float4*)&xls[(t0w + t) * 68 + f];
                g[t] = fmaf(xa.x, w0, fmaf(xa.y, w1, fmaf(xa.z, w2, fmaf(xa.w, w3v, g[t]))));
            }
        }
        #pragma unroll 2
        for (int e = 0; e < 32; e += 4) {
            const float w0 = fw2[(e + 0) * 64 + lane];
            const float w1 = fw2[(e + 1) * 64 + lane];
            const float w2 = fw2[(e + 2) * 64 + lane];
            const float w3v = fw2[(e + 3) * 64 + lane];
            #pragma unroll
            for (int t = 0; t < 8; ++t) {
                const float4 sa = *(const float4*)(sw + t * 32 + e);
                g[t] = fmaf(sa.x, w0, fmaf(sa.y, w1, fmaf(sa.z, w2, fmaf(sa.w, w3v, g[t]))));
            }
        }
        // egs rows are wave-private -> in-wave lgkmcnt ordering suffices
        #pragma unroll
        for (int t = 0; t < 8; ++t) egs[(t0w + t) * 64 + lane] = eluf(g[t]);

        float lg[8];
        const float b3 = fb3[lane];
        #pragma unroll
        for (int t = 0; t < 8; ++t) lg[t] = b3;
        #pragma unroll 2
        for (int h = 0; h < 64; h += 4) {
            const float w0 = fw3[(h + 0) * 64 + lane];
            const float w1 = fw3[(h + 1) * 64 + lane];
            const float w2 = fw3[(h + 2) * 64 + lane];
            const float w3v = fw3[(h + 3) * 64 + lane];
            #pragma unroll
            for (int t = 0; t < 8; ++t) {
                const float4 ev = *(const float4*)&egs[(t0w + t) * 64 + h];
                lg[t] = fmaf(ev.x, w0, fmaf(ev.y, w1, fmaf(ev.z, w2, fmaf(ev.w, w3v, lg[t]))));
            }
        }
        #pragma unroll
        for (int t = 0; t < 8; ++t) {
            float mx = lg[t];
            #pragma unroll
            for (int off = 32; off > 0; off >>= 1) mx = fmaxf(mx, __shfl_xor(mx, off));
            const float p = __expf(lg[t] - mx);
            float sm = p;
            #pragma unroll
            for (int off = 32; off > 0; off >>= 1) sm += __shfl_xor(sm, off);
            wts[(t0w + t) * 65 + lane] = p / sm;
        }
    }
    __syncthreads();   // gates ready; also fences egs before ped overlay reuse

    // ---- f-loop: 8 iters fully unrolled; B reused across 4 M-tiles ----
    const int f0 = wv * 8;
    f32x4 acc[4][4];   // [tile][u]
    #pragma unroll
    for (int tl = 0; tl < 4; ++tl)
        #pragma unroll
        for (int u = 0; u < 4; ++u) acc[tl][u] = (f32x4){0.f, 0.f, 0.f, 0.f};

    const uint4* bp = (const uint4*)img + (size_t)f0 * 512 + lane;
    #pragma unroll
    for (int ff = 0; ff < 8; ++ff) {
        const int f = f0 + ff;
        // 1) issue all 8 B-fragment loads (fly under the A-gen VALU below)
        uint4 B[8];
        #pragma unroll
        for (int i = 0; i < 8; ++i) B[i] = bp[(i >> 2) * 256 + (i & 3) * 64];
        bp += 512;
        // 2) per-tile gate/x scalars (LDS, broadcast-friendly)
        float xv[4], wt[4];
        #pragma unroll
        for (int tl = 0; tl < 4; ++tl) {
            xv[tl] = xls[(tl * 16 + m) * 68 + f];
            wt[tl] = wts[(tl * 16 + m) * 65 + f];
        }
        // 3) A-gen (w1/b1 amortized over 4 tiles) + 32 MFMA
        #pragma unroll
        for (int c = 0; c < 2; ++c) {
            const float* w1p = ew1 + f * 64 + c * 32 + quad * 8;
            const float* b1p = eb1 + f * 64 + c * 32 + quad * 8;
            const float4 wa = *(const float4*)w1p, wb = *(const float4*)(w1p + 4);
            const float4 ba = *(const float4*)b1p, bb = *(const float4*)(b1p + 4);
            const float wr[8] = {wa.x, wa.y, wa.z, wa.w, wb.x, wb.y, wb.z, wb.w};
            const float br[8] = {ba.x, ba.y, ba.z, ba.w, bb.x, bb.y, bb.z, bb.w};
            #pragma unroll
            for (int tl = 0; tl < 4; ++tl) {
                unsigned pw[4];
                #pragma unroll
                for (int p = 0; p < 4; ++p) {
                    const float v0 = wt[tl] * eluf(fmaf(xv[tl], wr[2 * p],     br[2 * p]));
                    const float v1 = wt[tl] * eluf(fmaf(xv[tl], wr[2 * p + 1], br[2 * p + 1]));
                    pw[p] = pack_bf16(v0, v1);
                }
                uint4 av; av.x = pw[0]; av.y = pw[1]; av.z = pw[2]; av.w = pw[3];
                const short8 a = *(short8*)&av;
                acc[tl][0] = __builtin_amdgcn_mfma_f32_16x16x32_bf16(a, *(short8*)&B[c * 4 + 0], acc[tl][0], 0, 0, 0);
                acc[tl][1] = __builtin_amdgcn_mfma_f32_16x16x32_bf16(a, *(short8*)&B[c * 4 + 1], acc[tl][1], 0, 0, 0);
                acc[tl][2] = __builtin_amdgcn_mfma_f32_16x16x32_bf16(a, *(short8*)&B[c * 4 + 2], acc[tl][2], 0, 0, 0);
                acc[tl][3] = __builtin_amdgcn_mfma_f32_16x16x32_bf16(a, *(short8*)&B[c * 4 + 3], acc[tl][3], 0, 0, 0);
            }
        }
    }

    // ---- bias K-chunk: wave wv<4 adds w_t @ eb3 for tile wv (once per tile) ----
    if (wv < 4) {
        const int tl = wv;
        const int trow = tl * 16 + m;
        const uint4* bq = (const uint4*)img + (size_t)64 * 512;
        #pragma unroll
        for (int c = 0; c < 2; ++c) {
            const int e0 = c * 32 + quad * 8;
            uint4 av;
            av.x = pack_bf16(wts[trow * 65 + e0 + 0], wts[trow * 65 + e0 + 1]);
            av.y = pack_bf16(wts[trow * 65 + e0 + 2], wts[trow * 65 + e0 + 3]);
            av.z = pack_bf16(wts[trow * 65 + e0 + 4], wts[trow * 65 + e0 + 5]);
            av.w = pack_bf16(wts[trow * 65 + e0 + 6], wts[trow * 65 + e0 + 7]);
            const short8 a = *(short8*)&av;
            #pragma unroll
            for (int u = 0; u < 4; ++u) {
                uint4 bv = bq[c * 256 + u * 64 + lane];
                acc[tl][u] = __builtin_amdgcn_mfma_f32_16x16x32_bf16(a, *(short8*)&bv, acc[tl][u], 0, 0, 0);
            }
        }
    }

    // ---- epilogue: per tile, 8-way butterfly through LDS, direct store ----
    // (C layout: row = quad*4+r, col = u*16+m) ; 2 barriers per tile
    #pragma unroll 1
    for (int tl = 0; tl < 4; ++tl) {
        #pragma unroll
        for (int u = 0; u < 4; ++u)
            #pragma unroll
            for (int r = 0; r < 4; ++r)
                ped[wv * 1088 + (quad * 4 + r) * 68 + u * 16 + m] = acc[tl][u][r];
        __syncthreads();
        {
            const int idx = tid * 2;
            const int tr = idx >> 6, k = idx & 63;
            float s0 = 0.f, s1 = 0.f;
            #pragma unroll
            for (int w = 0; w < 8; ++w) {
                const float2 v = *(const float2*)&ped[w * 1088 + tr * 68 + k];
                s0 += v.x; s1 += v.y;
            }
            *(float2*)(out + (size_t)(tokbase + tl * 16 + tr) * 64 + k) =
                make_float2(s0, s1);
        }
        __syncthreads();
    }
}

// ======================================================================
// Fallback (ws-free), validated R8 structure: 1024 blocks x 512 thr, 16 tok
// ======================================================================
__device__ __forceinline__ void gen_a_fb(const float* __restrict__ ew1,
                                         const float* __restrict__ eb1,
                                         int f, int quad, float xv, float wt,
                                         short8* a) {
    #pragma unroll
    for (int c = 0; c < 2; ++c) {
        const float* w1p = ew1 + f * 64 + c * 32 + quad * 8;
        const float* b1p = eb1 + f * 64 + c * 32 + quad * 8;
        const float4 w1a = *(const float4*)w1p, w1b = *(const float4*)(w1p + 4);
        const float4 b1a = *(const float4*)b1p, b1b = *(const float4*)(b1p + 4);
        uint4 av;
        av.x = pack_bf16(wt * eluf(fmaf(xv, w1a.x, b1a.x)),
                         wt * eluf(fmaf(xv, w1a.y, b1a.y)));
        av.y = pack_bf16(wt * eluf(fmaf(xv, w1a.z, b1a.z)),
                         wt * eluf(fmaf(xv, w1a.w, b1a.w)));
        av.z = pack_bf16(wt * eluf(fmaf(xv, w1b.x, b1b.x)),
                         wt * eluf(fmaf(xv, w1b.y, b1b.y)));
        av.w = pack_bf16(wt * eluf(fmaf(xv, w1b.z, b1b.z)),
                         wt * eluf(fmaf(xv, w1b.w, b1b.w)));
        a[c] = *(short8*)&av;
    }
}
__device__ __forceinline__ void gen_b_fp32(const float* __restrict__ w3f,
                                           int quad, int m, short8 b[2][4]) {
    #pragma unroll
    for (int c = 0; c < 2; ++c)
        #pragma unroll
        for (int u = 0; u < 4; ++u) {
            const float* wp = w3f + (size_t)(c * 32 + quad * 8) * 64 + u * 16 + m;
            uint4 v;
            v.x = pack_bf16(wp[0],   wp[64]);
            v.y = pack_bf16(wp[128], wp[192]);
            v.z = pack_bf16(wp[256], wp[320]);
            v.w = pack_bf16(wp[384], wp[448]);
            b[c][u] = *(short8*)&v;
        }
}

__global__ __launch_bounds__(512, 8)
void moe_fb(const float* __restrict__ x,   const float* __restrict__ s,
            const float* __restrict__ fw1, const float* __restrict__ fb1,
            const float* __restrict__ fw2, const float* __restrict__ fb2,
            const float* __restrict__ fw3, const float* __restrict__ fb3,
            const float* __restrict__ ew1, const float* __restrict__ eb1,
            const float* __restrict__ ew3, const float* __restrict__ eb3,
            float* __restrict__ out)
{
    __shared__ __align__(16) float xls[16 * 68];
    __shared__ __align__(16) float wts[16 * 65];
    __shared__ __align__(16) float egs[16 * 64];
    __shared__ __align__(16) float ped[4][16 * 68];

    const int tid = threadIdx.x;
    const int wv = tid >> 6, lane = tid & 63;
    const int tokbase = blockIdx.x * 16;

    if (tid < 256) {
        const int t = tid >> 4, fq = (tid & 15) * 4;
        *(float4*)&xls[t * 68 + fq] =
            *(const float4*)(x + (size_t)(tokbase + t) * 64 + fq);
    }
    __syncthreads();
    {
        const int t0w = wv * 2;
        const float* sw = s + (size_t)(tokbase + t0w) * 32;
        float g0, g1;
        g0 = g1 = fb1[lane] + fb2[lane];
        #pragma unroll 2
        for (int ff = 0; ff < 64; ff += 4) {
            const float4 xa = *(const float4*)&xls[(t0w + 0) * 68 + ff];
            const float4 xb = *(const float4*)&xls[(t0w + 1) * 68 + ff];
            const float w0 = fw1[(ff + 0) * 64 + lane];
            const float w1 = fw1[(ff + 1) * 64 + lane];
            const float w2 = fw1[(ff + 2) * 64 + lane];
            const float w3v = fw1[(ff + 3) * 64 + lane];
            g0 = fmaf(xa.x, w0, fmaf(xa.y, w1, fmaf(xa.z, w2, fmaf(xa.w, w3v, g0))));
            g1 = fmaf(xb.x, w0, fmaf(xb.y, w1, fmaf(xb.z, w2, fmaf(xb.w, w3v, g1))));
        }
        #pragma unroll 2
        for (int e = 0; e < 32; e += 4) {
            const float4 sa = *(const float4*)(sw + e);
            const float4 sb = *(const float4*)(sw + 32 + e);
            const float w0 = fw2[(e + 0) * 64 + lane];
            const float w1 = fw2[(e + 1) * 64 + lane];
            const float w2 = fw2[(e + 2) * 64 + lane];
            const float w3v = fw2[(e + 3) * 64 + lane];
            g0 = fmaf(sa.x, w0, fmaf(sa.y, w1, fmaf(sa.z, w2, fmaf(sa.w, w3v, g0))));
            g1 = fmaf(sb.x, w0, fmaf(sb.y, w1, fmaf(sb.z, w2, fmaf(sb.w, w3v, g1))));
        }
        egs[(t0w + 0) * 64 + lane] = eluf(g0);
        egs[(t0w + 1) * 64 + lane] = eluf(g1);
        float lg0 = fb3[lane], lg1 = lg0;
        #pragma unroll 2
        for (int h = 0; h < 64; h += 4) {
            const float4 e0 = *(const float4*)&egs[(t0w + 0) * 64 + h];
            const float4 e1 = *(const float4*)&egs[(t0w + 1) * 64 + h];
            const float w0 = fw3[(h + 0) * 64 + lane];
            const float w1 = fw3[(h + 1) * 64 + lane];
            const float w2 = fw3[(h + 2) * 64 + lane];
            const float w3v = fw3[(h + 3) * 64 + lane];
            lg0 = fmaf(e0.x, w0, fmaf(e0.y, w1, fmaf(e0.z, w2, fmaf(e0.w, w3v, lg0))));
            lg1 = fmaf(e1.x, w0, fmaf(e1.y, w1, fmaf(e1.z, w2, fmaf(e1.w, w3v, lg1))));
        }
        float mx0 = lg0, mx1 = lg1;
        #pragma unroll
        for (int off = 32; off > 0; off >>= 1) {
            mx0 = fmaxf(mx0, __shfl_xor(mx0, off));
            mx1 = fmaxf(mx1, __shfl_xor(mx1, off));
        }
        const float p0 = __expf(lg0 - mx0), p1 = __expf(lg1 - mx1);
        float s0 = p0, s1 = p1;
        #pragma unroll
        for (int off = 32; off > 0; off >>= 1) {
            s0 += __shfl_xor(s0, off);
            s1 += __shfl_xor(s1, off);
        }
        wts[(t0w + 0) * 65 + lane] = p0 / s0;
        wts[(t0w + 1) * 65 + lane] = p1 / s1;
    }
    __syncthreads();

    const int m = tid & 15, quad = (tid >> 4) & 3;
    const int f0 = wv * 8;
    f32x4 acc[4];
    #pragma unroll
    for (int u = 0; u < 4; ++u) acc[u] = (f32x4){0.f, 0.f, 0.f, 0.f};

    #pragma unroll 1
    for (int ff = 0; ff < 8; ++ff) {
        const int fcur = f0 + ff;
        short8 b[2][4], a[2];
        gen_b_fp32(ew3 + (size_t)fcur * 4096, quad, m, b);
        gen_a_fb(ew1, eb1, fcur, quad, xls[m * 68 + fcur], wts[m * 65 + fcur], a);
        #pragma unroll
        for (int u = 0; u < 4; ++u) {
            acc[u] = __builtin_amdgcn_mfma_f32_16x16x32_bf16(a[0], b[0][u], acc[u], 0, 0, 0);
            acc[u] = __builtin_amdgcn_mfma_f32_16x16x32_bf16(a[1], b[1][u], acc[u], 0, 0, 0);
        }
    }
    if (wv < 2) {
        const int e0 = wv * 32 + quad * 8;
        uint4 av;
        av.x = pack_bf16(wts[m * 65 + e0 + 0], wts[m * 65 + e0 + 1]);
        av.y = pack_bf16(wts[m * 65 + e0 + 2], wts[m * 65 + e0 + 3]);
        av.z = pack_bf16(wts[m * 65 + e0 + 4], wts[m * 65 + e0 + 5]);
        av.w = pack_bf16(wts[m * 65 + e0 + 6], wts[m * 65 + e0 + 7]);
        short8 a = *(short8*)&av;
        #pragma unroll
        for (int u = 0; u < 4; ++u) {
            const float* wp = eb3 + (size_t)e0 * 64 + u * 16 + m;
            uint4 bv;
            bv.x = pack_bf16(wp[0],   wp[64]);
            bv.y = pack_bf16(wp[128], wp[192]);
            bv.z = pack_bf16(wp[256], wp[320]);
            bv.w = pack_bf16(wp[384], wp[448]);
            acc[u] = __builtin_amdgcn_mfma_f32_16x16x32_bf16(a, *(short8*)&bv, acc[u], 0, 0, 0);
        }
    }
    if (wv >= 4) {
        #pragma unroll
        for (int u = 0; u < 4; ++u)
            #pragma unroll
            for (int r = 0; r < 4; ++r)
                ped[wv - 4][(quad * 4 + r) * 68 + u * 16 + m] = acc[u][r];
    }
    __syncthreads();
    if (wv < 4) {
        #pragma unroll
        for (int u = 0; u < 4; ++u)
            #pragma unroll
            for (int r = 0; r < 4; ++r)
                acc[u][r] += ped[wv][(quad * 4 + r) * 68 + u * 16 + m];
    }
    __syncthreads();
    if (wv == 2 || wv == 3) {
        #pragma unroll
        for (int u = 0; u < 4; ++u)
            #pragma unroll
            for (int r = 0; r < 4; ++r)
                ped[wv - 2][(quad * 4 + r) * 68 + u * 16 + m] = acc[u][r];
    }
    __syncthreads();
    if (wv < 2) {
        #pragma unroll
        for (int u = 0; u < 4; ++u)
            #pragma unroll
            for (int r = 0; r < 4; ++r)
                acc[u][r] += ped[wv][(quad * 4 + r) * 68 + u * 16 + m];
    }
    __syncthreads();
    if (wv == 1) {
        #pragma unroll
        for (int u = 0; u < 4; ++u)
            #pragma unroll
            for (int r = 0; r < 4; ++r)
                ped[0][(quad * 4 + r) * 68 + u * 16 + m] = acc[u][r];
    }
    __syncthreads();
    if (wv == 0) {
        #pragma unroll
        for (int u = 0; u < 4; ++u)
            #pragma unroll
            for (int r = 0; r < 4; ++r)
                ped[0][(quad * 4 + r) * 68 + u * 16 + m] += acc[u][r];
    }
    __syncthreads();
    if (tid < 256) {
        const int t = tid >> 4, kq = tid & 15;
        float4 o = *(const float4*)&ped[0][t * 68 + kq * 4];
        *(float4*)(out + (size_t)(tokbase + t) * 64 + kq * 4) = o;
    }
}

extern "C" void kernel_launch(void* const* d_in, const int* in_sizes, int n_in,
                              void* d_out, int out_size, void* d_ws, size_t ws_size,
                              hipStream_t stream) {
    const float* x   = (const float*)d_in[0];
    const float* s   = (const float*)d_in[1];
    const float* fw1 = (const float*)d_in[2];
    const float* fb1 = (const float*)d_in[3];
    const float* fw2 = (const float*)d_in[4];
    const float* fb2 = (const float*)d_in[5];
    const float* fw3 = (const float*)d_in[6];
    const float* fb3 = (const float*)d_in[7];
    const float* ew1 = (const float*)d_in[8];
    const float* eb1 = (const float*)d_in[9];
    const float* ew3 = (const float*)d_in[10];
    const float* eb3 = (const float*)d_in[11];
    float* out = (float*)d_out;

    const size_t ws_need = (size_t)65 * 4096 * sizeof(unsigned short);  // 532,480 B
    if (ws_size >= ws_need && (((uintptr_t)d_ws & 15) == 0)) {
        unsigned short* img = (unsigned short*)d_ws;
        prepass<<<dim3(65), dim3(256), 0, stream>>>(ew3, eb3, img);
        moe_main<<<dim3(NTOK / 64), dim3(512), 0, stream>>>(
            x, s, fw1, fb1, fw2, fb2, fw3, fb3, ew1, eb1, ew3, eb3, img, out);
    } else {
        moe_fb<<<dim3(NTOK / 16), dim3(512), 0, stream>>>(
            x, s, fw1, fb1, fw2, fb2, fw3, fb3, ew1, eb1, ew3, eb3, out);
    }
}

// Round 11
// 146.028 us; speedup vs baseline: 1.6479x; 1.6479x over previous
//
#include <hip/hip_runtime.h>
#include <hip/hip_bf16.h>
#include <math.h>

// B=32,T=512 -> NTOK=16384 tokens; F=64; H=64; E=32
#define NTOK 16384

typedef __attribute__((ext_vector_type(8))) short short8;   // 8 bf16 (MFMA A/B)
typedef __attribute__((ext_vector_type(4))) float f32x4;    // MFMA acc

__device__ __forceinline__ unsigned pack_bf16(float a, float b) {
    union { __hip_bfloat162 h; unsigned u; } cv;
    cv.h = __float22bfloat162_rn(make_float2(a, b));
    return cv.u;
}
__device__ __forceinline__ float eluf(float z) {
    return z > 0.0f ? z : (__expf(z) - 1.0f);
}

// ---------------- prepass: fragment-major bf16 B images ----------------
// slot f (0..63): B = ew3[f] (rows k=h, cols n); slot 64: B = eb3 (rows e, cols n)
// image[f][idx] uint4, idx = c*256 + u*64 + lane:
//   elem j of lane's short8 = B[c*32 + (lane>>4)*8 + j][u*16 + (lane&15)]
__global__ __launch_bounds__(256)
void prepass(const float* __restrict__ ew3, const float* __restrict__ eb3,
             unsigned short* __restrict__ ws) {
    __shared__ float tile[64 * 65];
    const int bid = blockIdx.x, tid = threadIdx.x;
    const float* src = (bid < 64) ? (ew3 + (size_t)bid * 4096) : eb3;

    const int r = tid >> 2, c0 = (tid & 3) * 16;
    #pragma unroll
    for (int j = 0; j < 4; ++j) {
        float4 v = *(const float4*)(src + r * 64 + c0 + j * 4);
        tile[r * 65 + c0 + j * 4 + 0] = v.x;
        tile[r * 65 + c0 + j * 4 + 1] = v.y;
        tile[r * 65 + c0 + j * 4 + 2] = v.z;
        tile[r * 65 + c0 + j * 4 + 3] = v.w;
    }
    __syncthreads();

    uint4* dst = (uint4*)(ws + (size_t)bid * 4096);
    #pragma unroll
    for (int it = 0; it < 2; ++it) {
        const int idx = tid + it * 256;
        const int c = idx >> 8, u = (idx >> 6) & 3, l = idx & 63;
        const int m = l & 15, q = (l >> 4) & 3;
        const int rb = c * 32 + q * 8, col = u * 16 + m;
        unsigned pw[4];
        #pragma unroll
        for (int p = 0; p < 4; ++p)
            pw[p] = pack_bf16(tile[(rb + 2 * p) * 65 + col],
                              tile[(rb + 2 * p + 1) * 65 + col]);
        uint4 pk; pk.x = pw[0]; pk.y = pw[1]; pk.z = pw[2]; pk.w = pw[3];
        dst[idx] = pk;
    }
}

// A-frag gen for TWO token tiles sharing expert weights.
__device__ __forceinline__ void gen_a2(const float* __restrict__ ew1,
                                       const float* __restrict__ eb1,
                                       int f, int quad,
                                       float xv0, float wt0, float xv1, float wt1,
                                       short8* a0, short8* a1) {
    #pragma unroll
    for (int c = 0; c < 2; ++c) {
        const float* w1p = ew1 + f * 64 + c * 32 + quad * 8;
        const float* b1p = eb1 + f * 64 + c * 32 + quad * 8;
        const float4 wa = *(const float4*)w1p, wb = *(const float4*)(w1p + 4);
        const float4 ba = *(const float4*)b1p, bb = *(const float4*)(b1p + 4);
        uint4 v0, v1;
        v0.x = pack_bf16(wt0 * eluf(fmaf(xv0, wa.x, ba.x)),
                         wt0 * eluf(fmaf(xv0, wa.y, ba.y)));
        v0.y = pack_bf16(wt0 * eluf(fmaf(xv0, wa.z, ba.z)),
                         wt0 * eluf(fmaf(xv0, wa.w, ba.w)));
        v0.z = pack_bf16(wt0 * eluf(fmaf(xv0, wb.x, bb.x)),
                         wt0 * eluf(fmaf(xv0, wb.y, bb.y)));
        v0.w = pack_bf16(wt0 * eluf(fmaf(xv0, wb.z, bb.z)),
                         wt0 * eluf(fmaf(xv0, wb.w, bb.w)));
        v1.x = pack_bf16(wt1 * eluf(fmaf(xv1, wa.x, ba.x)),
                         wt1 * eluf(fmaf(xv1, wa.y, ba.y)));
        v1.y = pack_bf16(wt1 * eluf(fmaf(xv1, wa.z, ba.z)),
                         wt1 * eluf(fmaf(xv1, wa.w, ba.w)));
        v1.z = pack_bf16(wt1 * eluf(fmaf(xv1, wb.x, bb.x)),
                         wt1 * eluf(fmaf(xv1, wb.y, bb.y)));
        v1.w = pack_bf16(wt1 * eluf(fmaf(xv1, wb.z, bb.z)),
                         wt1 * eluf(fmaf(xv1, wb.w, bb.w)));
        a0[c] = *(short8*)&v0;
        a1[c] = *(short8*)&v1;
    }
}

// ---------------- main kernel: 512 blocks x 512 thr (8 waves) ----------------
// block = 32 tokens; wave wv: f in [wv*8, wv*8+8), TWO 16-token M-tiles.
// R11 = R8 (proven 47us) + LDS overlay (egs<->ped) -> 51.8 KB -> 3 blocks/CU.
// f-loop stays FULLY UNROLLED (R9's rolled loop de-pipelined the B-loads);
// all register arrays statically indexed (R10's dynamic acc[tl] spilled).
__global__ __launch_bounds__(512, 6)
void moe_main(const float* __restrict__ x,   const float* __restrict__ s,
              const float* __restrict__ fw1, const float* __restrict__ fb1,
              const float* __restrict__ fw2, const float* __restrict__ fb2,
              const float* __restrict__ fw3, const float* __restrict__ fb3,
              const float* __restrict__ ew1, const float* __restrict__ eb1,
              const float* __restrict__ ew3, const float* __restrict__ eb3,
              const unsigned short* __restrict__ img,
              float* __restrict__ out)
{
    // xls [0,8704) | wts [8704,17024) | scr [17024,51840):
    //   gating: egs (8192 B)   epilogue: ped0 (17408 B) + ped1 (17408 B)
    __shared__ __align__(16) char smem[51840];
    float* xls = (float*)smem;                      // [32][68]
    float* wts = (float*)(smem + 8704);             // [32][65]
    float* egs = (float*)(smem + 17024);            // [32][64] (gating only)
    float* ped0 = (float*)(smem + 17024);           // [4][16*68] (epilogue)
    float* ped1 = (float*)(smem + 17024 + 17408);   // [4][16*68]

    const int tid = threadIdx.x;
    const int wv = tid >> 6, lane = tid & 63;
    const int m = tid & 15, quad = (tid >> 4) & 3;
    const int tokbase = blockIdx.x * 32;

    // ---- stage x tile: 32 rows x 16 float4 = 512 ----
    {
        const int t = tid >> 4, fq = (tid & 15) * 4;
        *(float4*)&xls[t * 68 + fq] =
            *(const float4*)(x + (size_t)(tokbase + t) * 64 + fq);
    }
    __syncthreads();

    // ---- gating: each wave -> softmax gates for its 4 tokens ----
    {
        const int t0w = wv * 4;
        const float* sw = s + (size_t)(tokbase + t0w) * 32;
        float g[4];
        const float b0 = fb1[lane] + fb2[lane];
        #pragma unroll
        for (int t = 0; t < 4; ++t) g[t] = b0;
        for (int f = 0; f < 64; f += 4) {
            const float w0 = fw1[(f + 0) * 64 + lane];
            const float w1 = fw1[(f + 1) * 64 + lane];
            const float w2 = fw1[(f + 2) * 64 + lane];
            const float w3v = fw1[(f + 3) * 64 + lane];
            #pragma unroll
            for (int t = 0; t < 4; ++t) {
                const float4 xa = *(const float4*)&xls[(t0w + t) * 68 + f];
                g[t] = fmaf(xa.x, w0, fmaf(xa.y, w1, fmaf(xa.z, w2, fmaf(xa.w, w3v, g[t]))));
            }
        }
        for (int e = 0; e < 32; e += 4) {
            const float w0 = fw2[(e + 0) * 64 + lane];
            const float w1 = fw2[(e + 1) * 64 + lane];
            const float w2 = fw2[(e + 2) * 64 + lane];
            const float w3v = fw2[(e + 3) * 64 + lane];
            #pragma unroll
            for (int t = 0; t < 4; ++t) {
                const float4 sa = *(const float4*)(sw + t * 32 + e);
                g[t] = fmaf(sa.x, w0, fmaf(sa.y, w1, fmaf(sa.z, w2, fmaf(sa.w, w3v, g[t]))));
            }
        }
        // egs rows are wave-private -> in-wave lgkmcnt ordering suffices
        #pragma unroll
        for (int t = 0; t < 4; ++t) egs[(t0w + t) * 64 + lane] = eluf(g[t]);

        float lg[4];
        const float b3 = fb3[lane];
        #pragma unroll
        for (int t = 0; t < 4; ++t) lg[t] = b3;
        for (int h = 0; h < 64; h += 4) {
            const float w0 = fw3[(h + 0) * 64 + lane];
            const float w1 = fw3[(h + 1) * 64 + lane];
            const float w2 = fw3[(h + 2) * 64 + lane];
            const float w3v = fw3[(h + 3) * 64 + lane];
            #pragma unroll
            for (int t = 0; t < 4; ++t) {
                const float4 ev = *(const float4*)&egs[(t0w + t) * 64 + h];
                lg[t] = fmaf(ev.x, w0, fmaf(ev.y, w1, fmaf(ev.z, w2, fmaf(ev.w, w3v, lg[t]))));
            }
        }
        #pragma unroll
        for (int t = 0; t < 4; ++t) {
            float mx = lg[t];
            #pragma unroll
            for (int off = 32; off > 0; off >>= 1) mx = fmaxf(mx, __shfl_xor(mx, off));
            const float p = __expf(lg[t] - mx);
            float sm = p;
            #pragma unroll
            for (int off = 32; off > 0; off >>= 1) sm += __shfl_xor(sm, off);
            wts[(t0w + t) * 65 + lane] = p / sm;
        }
    }
    __syncthreads();   // gates ready; also fences egs-reads before ped overlay use

    // ---- f-loop: 8 iters FULLY UNROLLED; B in VGPRs reused across 2 M-tiles ----
    const int f0 = wv * 8;
    f32x4 acc0[4], acc1[4];
    #pragma unroll
    for (int u = 0; u < 4; ++u) {
        acc0[u] = (f32x4){0.f, 0.f, 0.f, 0.f};
        acc1[u] = (f32x4){0.f, 0.f, 0.f, 0.f};
    }

    const uint4* bp = (const uint4*)img + (size_t)f0 * 512 + lane;
    #pragma unroll
    for (int ff = 0; ff < 8; ++ff) {
        const int f = f0 + ff;
        // 1) issue all 8 B-fragment loads (fly under the A-gen VALU below)
        uint4 b0 = bp[0 * 64];
        uint4 b1 = bp[1 * 64];
        uint4 b2 = bp[2 * 64];
        uint4 b3 = bp[3 * 64];
        uint4 b4 = bp[256 + 0 * 64];
        uint4 b5 = bp[256 + 1 * 64];
        uint4 b6 = bp[256 + 2 * 64];
        uint4 b7 = bp[256 + 3 * 64];
        bp += 512;
        // 2) A-gen for both tiles hides the load latency
        const float xv0 = xls[m * 68 + f];
        const float wt0 = wts[m * 65 + f];
        const float xv1 = xls[(16 + m) * 68 + f];
        const float wt1 = wts[(16 + m) * 65 + f];
        short8 a0[2], a1[2];
        gen_a2(ew1, eb1, f, quad, xv0, wt0, xv1, wt1, a0, a1);
        // 3) 16 MFMA: B reused across tiles
        acc0[0] = __builtin_amdgcn_mfma_f32_16x16x32_bf16(a0[0], *(short8*)&b0, acc0[0], 0, 0, 0);
        acc0[1] = __builtin_amdgcn_mfma_f32_16x16x32_bf16(a0[0], *(short8*)&b1, acc0[1], 0, 0, 0);
        acc0[2] = __builtin_amdgcn_mfma_f32_16x16x32_bf16(a0[0], *(short8*)&b2, acc0[2], 0, 0, 0);
        acc0[3] = __builtin_amdgcn_mfma_f32_16x16x32_bf16(a0[0], *(short8*)&b3, acc0[3], 0, 0, 0);
        acc1[0] = __builtin_amdgcn_mfma_f32_16x16x32_bf16(a1[0], *(short8*)&b0, acc1[0], 0, 0, 0);
        acc1[1] = __builtin_amdgcn_mfma_f32_16x16x32_bf16(a1[0], *(short8*)&b1, acc1[1], 0, 0, 0);
        acc1[2] = __builtin_amdgcn_mfma_f32_16x16x32_bf16(a1[0], *(short8*)&b2, acc1[2], 0, 0, 0);
        acc1[3] = __builtin_amdgcn_mfma_f32_16x16x32_bf16(a1[0], *(short8*)&b3, acc1[3], 0, 0, 0);
        acc0[0] = __builtin_amdgcn_mfma_f32_16x16x32_bf16(a0[1], *(short8*)&b4, acc0[0], 0, 0, 0);
        acc0[1] = __builtin_amdgcn_mfma_f32_16x16x32_bf16(a0[1], *(short8*)&b5, acc0[1], 0, 0, 0);
        acc0[2] = __builtin_amdgcn_mfma_f32_16x16x32_bf16(a0[1], *(short8*)&b6, acc0[2], 0, 0, 0);
        acc0[3] = __builtin_amdgcn_mfma_f32_16x16x32_bf16(a0[1], *(short8*)&b7, acc0[3], 0, 0, 0);
        acc1[0] = __builtin_amdgcn_mfma_f32_16x16x32_bf16(a1[1], *(short8*)&b4, acc1[0], 0, 0, 0);
        acc1[1] = __builtin_amdgcn_mfma_f32_16x16x32_bf16(a1[1], *(short8*)&b5, acc1[1], 0, 0, 0);
        acc1[2] = __builtin_amdgcn_mfma_f32_16x16x32_bf16(a1[1], *(short8*)&b6, acc1[2], 0, 0, 0);
        acc1[3] = __builtin_amdgcn_mfma_f32_16x16x32_bf16(a1[1], *(short8*)&b7, acc1[3], 0, 0, 0);
    }

    // ---- bias K-chunk: waves 0..3 = {tile} x {e-half} ----
    if (wv < 4) {
        const int tile = wv >> 1, eh = wv & 1;
        const int e0 = eh * 32 + quad * 8;
        const int trow = tile * 16 + m;
        uint4 av;
        av.x = pack_bf16(wts[trow * 65 + e0 + 0], wts[trow * 65 + e0 + 1]);
        av.y = pack_bf16(wts[trow * 65 + e0 + 2], wts[trow * 65 + e0 + 3]);
        av.z = pack_bf16(wts[trow * 65 + e0 + 4], wts[trow * 65 + e0 + 5]);
        av.w = pack_bf16(wts[trow * 65 + e0 + 6], wts[trow * 65 + e0 + 7]);
        short8 a = *(short8*)&av;
        const uint4* bq = (const uint4*)img + (size_t)64 * 512;
        if (tile == 0) {
            #pragma unroll
            for (int u = 0; u < 4; ++u) {
                uint4 bv = bq[eh * 256 + u * 64 + lane];
                acc0[u] = __builtin_amdgcn_mfma_f32_16x16x32_bf16(a, *(short8*)&bv, acc0[u], 0, 0, 0);
            }
        } else {
            #pragma unroll
            for (int u = 0; u < 4; ++u) {
                uint4 bv = bq[eh * 256 + u * 64 + lane];
                acc1[u] = __builtin_amdgcn_mfma_f32_16x16x32_bf16(a, *(short8*)&bv, acc1[u], 0, 0, 0);
            }
        }
    }

    // ---- tree reduction over 8 wave-partials, both tiles in parallel ----
    // (C layout: row = quad*4+r, col = u*16+m)
    if (wv >= 4) {
        #pragma unroll
        for (int u = 0; u < 4; ++u)
            #pragma unroll
            for (int r = 0; r < 4; ++r) {
                const int idx = (quad * 4 + r) * 68 + u * 16 + m;
                ped0[(wv - 4) * 1088 + idx] = acc0[u][r];
                ped1[(wv - 4) * 1088 + idx] = acc1[u][r];
            }
    }
    __syncthreads();
    if (wv < 4) {
        #pragma unroll
        for (int u = 0; u < 4; ++u)
            #pragma unroll
            for (int r = 0; r < 4; ++r) {
                const int idx = (quad * 4 + r) * 68 + u * 16 + m;
                acc0[u][r] += ped0[wv * 1088 + idx];
                acc1[u][r] += ped1[wv * 1088 + idx];
            }
    }
    __syncthreads();
    if (wv == 2 || wv == 3) {
        #pragma unroll
        for (int u = 0; u < 4; ++u)
            #pragma unroll
            for (int r = 0; r < 4; ++r) {
                const int idx = (quad * 4 + r) * 68 + u * 16 + m;
                ped0[(wv - 2) * 1088 + idx] = acc0[u][r];
                ped1[(wv - 2) * 1088 + idx] = acc1[u][r];
            }
    }
    __syncthreads();
    if (wv < 2) {
        #pragma unroll
        for (int u = 0; u < 4; ++u)
            #pragma unroll
            for (int r = 0; r < 4; ++r) {
                const int idx = (quad * 4 + r) * 68 + u * 16 + m;
                acc0[u][r] += ped0[wv * 1088 + idx];
                acc1[u][r] += ped1[wv * 1088 + idx];
            }
    }
    __syncthreads();
    if (wv == 1) {
        #pragma unroll
        for (int u = 0; u < 4; ++u)
            #pragma unroll
            for (int r = 0; r < 4; ++r) {
                const int idx = (quad * 4 + r) * 68 + u * 16 + m;
                ped0[idx] = acc0[u][r];
                ped1[idx] = acc1[u][r];
            }
    }
    __syncthreads();
    if (wv == 0) {
        #pragma unroll
        for (int u = 0; u < 4; ++u)
            #pragma unroll
            for (int r = 0; r < 4; ++r) {
                const int idx = (quad * 4 + r) * 68 + u * 16 + m;
                ped0[idx] += acc0[u][r];
                ped1[idx] += acc1[u][r];
            }
    }
    __syncthreads();

    // ---- final store: 32 tokens x 16 float4, coalesced ----
    {
        const int t = tid >> 4, kq = tid & 15;
        const float* srcp = (t < 16) ? &ped0[t * 68 + kq * 4]
                                     : &ped1[(t - 16) * 68 + kq * 4];
        *(float4*)(out + (size_t)(tokbase + t) * 64 + kq * 4) = *(const float4*)srcp;
    }
}

// ======================================================================
// Fallback (ws-free), validated R5/R8 structure: 1024 blocks x 512 thr, 16 tok
// ======================================================================
__device__ __forceinline__ void gen_a_fb(const float* __restrict__ ew1,
                                         const float* __restrict__ eb1,
                                         int f, int quad, float xv, float wt,
                                         short8* a) {
    #pragma unroll
    for (int c = 0; c < 2; ++c) {
        const float* w1p = ew1 + f * 64 + c * 32 + quad * 8;
        const float* b1p = eb1 + f * 64 + c * 32 + quad * 8;
        const float4 w1a = *(const float4*)w1p, w1b = *(const float4*)(w1p + 4);
        const float4 b1a = *(const float4*)b1p, b1b = *(const float4*)(b1p + 4);
        uint4 av;
        av.x = pack_bf16(wt * eluf(fmaf(xv, w1a.x, b1a.x)),
                         wt * eluf(fmaf(xv, w1a.y, b1a.y)));
        av.y = pack_bf16(wt * eluf(fmaf(xv, w1a.z, b1a.z)),
                         wt * eluf(fmaf(xv, w1a.w, b1a.w)));
        av.z = pack_bf16(wt * eluf(fmaf(xv, w1b.x, b1b.x)),
                         wt * eluf(fmaf(xv, w1b.y, b1b.y)));
        av.w = pack_bf16(wt * eluf(fmaf(xv, w1b.z, b1b.z)),
                         wt * eluf(fmaf(xv, w1b.w, b1b.w)));
        a[c] = *(short8*)&av;
    }
}
__device__ __forceinline__ void gen_b_fp32(const float* __restrict__ w3f,
                                           int quad, int m, short8 b[2][4]) {
    #pragma unroll
    for (int c = 0; c < 2; ++c)
        #pragma unroll
        for (int u = 0; u < 4; ++u) {
            const float* wp = w3f + (size_t)(c * 32 + quad * 8) * 64 + u * 16 + m;
            uint4 v;
            v.x = pack_bf16(wp[0],   wp[64]);
            v.y = pack_bf16(wp[128], wp[192]);
            v.z = pack_bf16(wp[256], wp[320]);
            v.w = pack_bf16(wp[384], wp[448]);
            b[c][u] = *(short8*)&v;
        }
}

__global__ __launch_bounds__(512, 8)
void moe_fb(const float* __restrict__ x,   const float* __restrict__ s,
            const float* __restrict__ fw1, const float* __restrict__ fb1,
            const float* __restrict__ fw2, const float* __restrict__ fb2,
            const float* __restrict__ fw3, const float* __restrict__ fb3,
            const float* __restrict__ ew1, const float* __restrict__ eb1,
            const float* __restrict__ ew3, const float* __restrict__ eb3,
            float* __restrict__ out)
{
    __shared__ __align__(16) float xls[16 * 68];
    __shared__ __align__(16) float wts[16 * 65];
    __shared__ __align__(16) float egs[16 * 64];
    __shared__ __align__(16) float ped[4][16 * 68];

    const int tid = threadIdx.x;
    const int wv = tid >> 6, lane = tid & 63;
    const int tokbase = blockIdx.x * 16;

    if (tid < 256) {
        const int t = tid >> 4, fq = (tid & 15) * 4;
        *(float4*)&xls[t * 68 + fq] =
            *(const float4*)(x + (size_t)(tokbase + t) * 64 + fq);
    }
    __syncthreads();
    {
        const int t0w = wv * 2;
        const float* sw = s + (size_t)(tokbase + t0w) * 32;
        float g0, g1;
        g0 = g1 = fb1[lane] + fb2[lane];
        for (int ff = 0; ff < 64; ff += 4) {
            const float4 xa = *(const float4*)&xls[(t0w + 0) * 68 + ff];
            const float4 xb = *(const float4*)&xls[(t0w + 1) * 68 + ff];
            const float w0 = fw1[(ff + 0) * 64 + lane];
            const float w1 = fw1[(ff + 1) * 64 + lane];
            const float w2 = fw1[(ff + 2) * 64 + lane];
            const float w3v = fw1[(ff + 3) * 64 + lane];
            g0 = fmaf(xa.x, w0, fmaf(xa.y, w1, fmaf(xa.z, w2, fmaf(xa.w, w3v, g0))));
            g1 = fmaf(xb.x, w0, fmaf(xb.y, w1, fmaf(xb.z, w2, fmaf(xb.w, w3v, g1))));
        }
        for (int e = 0; e < 32; e += 4) {
            const float4 sa = *(const float4*)(sw + e);
            const float4 sb = *(const float4*)(sw + 32 + e);
            const float w0 = fw2[(e + 0) * 64 + lane];
            const float w1 = fw2[(e + 1) * 64 + lane];
            const float w2 = fw2[(e + 2) * 64 + lane];
            const float w3v = fw2[(e + 3) * 64 + lane];
            g0 = fmaf(sa.x, w0, fmaf(sa.y, w1, fmaf(sa.z, w2, fmaf(sa.w, w3v, g0))));
            g1 = fmaf(sb.x, w0, fmaf(sb.y, w1, fmaf(sb.z, w2, fmaf(sb.w, w3v, g1))));
        }
        egs[(t0w + 0) * 64 + lane] = eluf(g0);
        egs[(t0w + 1) * 64 + lane] = eluf(g1);
        float lg0 = fb3[lane], lg1 = lg0;
        for (int h = 0; h < 64; h += 4) {
            const float4 e0 = *(const float4*)&egs[(t0w + 0) * 64 + h];
            const float4 e1 = *(const float4*)&egs[(t0w + 1) * 64 + h];
            const float w0 = fw3[(h + 0) * 64 + lane];
            const float w1 = fw3[(h + 1) * 64 + lane];
            const float w2 = fw3[(h + 2) * 64 + lane];
            const float w3v = fw3[(h + 3) * 64 + lane];
            lg0 = fmaf(e0.x, w0, fmaf(e0.y, w1, fmaf(e0.z, w2, fmaf(e0.w, w3v, lg0))));
            lg1 = fmaf(e1.x, w0, fmaf(e1.y, w1, fmaf(e1.z, w2, fmaf(e1.w, w3v, lg1))));
        }
        float mx0 = lg0, mx1 = lg1;
        #pragma unroll
        for (int off = 32; off > 0; off >>= 1) {
            mx0 = fmaxf(mx0, __shfl_xor(mx0, off));
            mx1 = fmaxf(mx1, __shfl_xor(mx1, off));
        }
        const float p0 = __expf(lg0 - mx0), p1 = __expf(lg1 - mx1);
        float s0 = p0, s1 = p1;
        #pragma unroll
        for (int off = 32; off > 0; off >>= 1) {
            s0 += __shfl_xor(s0, off);
            s1 += __shfl_xor(s1, off);
        }
        wts[(t0w + 0) * 65 + lane] = p0 / s0;
        wts[(t0w + 1) * 65 + lane] = p1 / s1;
    }
    __syncthreads();

    const int m = tid & 15, quad = (tid >> 4) & 3;
    const int f0 = wv * 8;
    f32x4 acc[4];
    #pragma unroll
    for (int u = 0; u < 4; ++u) acc[u] = (f32x4){0.f, 0.f, 0.f, 0.f};

    #pragma unroll
    for (int ff = 0; ff < 8; ++ff) {
        const int fcur = f0 + ff;
        short8 b[2][4], a[2];
        gen_b_fp32(ew3 + (size_t)fcur * 4096, quad, m, b);
        gen_a_fb(ew1, eb1, fcur, quad, xls[m * 68 + fcur], wts[m * 65 + fcur], a);
        #pragma unroll
        for (int u = 0; u < 4; ++u) {
            acc[u] = __builtin_amdgcn_mfma_f32_16x16x32_bf16(a[0], b[0][u], acc[u], 0, 0, 0);
            acc[u] = __builtin_amdgcn_mfma_f32_16x16x32_bf16(a[1], b[1][u], acc[u], 0, 0, 0);
        }
    }
    if (wv < 2) {
        const int e0 = wv * 32 + quad * 8;
        uint4 av;
        av.x = pack_bf16(wts[m * 65 + e0 + 0], wts[m * 65 + e0 + 1]);
        av.y = pack_bf16(wts[m * 65 + e0 + 2], wts[m * 65 + e0 + 3]);
        av.z = pack_bf16(wts[m * 65 + e0 + 4], wts[m * 65 + e0 + 5]);
        av.w = pack_bf16(wts[m * 65 + e0 + 6], wts[m * 65 + e0 + 7]);
        short8 a = *(short8*)&av;
        #pragma unroll
        for (int u = 0; u < 4; ++u) {
            const float* wp = eb3 + (size_t)e0 * 64 + u * 16 + m;
            uint4 bv;
            bv.x = pack_bf16(wp[0],   wp[64]);
            bv.y = pack_bf16(wp[128], wp[192]);
            bv.z = pack_bf16(wp[256], wp[320]);
            bv.w = pack_bf16(wp[384], wp[448]);
            acc[u] = __builtin_amdgcn_mfma_f32_16x16x32_bf16(a, *(short8*)&bv, acc[u], 0, 0, 0);
        }
    }
    if (wv >= 4) {
        #pragma unroll
        for (int u = 0; u < 4; ++u)
            #pragma unroll
            for (int r = 0; r < 4; ++r)
                ped[wv - 4][(quad * 4 + r) * 68 + u * 16 + m] = acc[u][r];
    }
    __syncthreads();
    if (wv < 4) {
        #pragma unroll
        for (int u = 0; u < 4; ++u)
            #pragma unroll
            for (int r = 0; r < 4; ++r)
                acc[u][r] += ped[wv][(quad * 4 + r) * 68 + u * 16 + m];
    }
    __syncthreads();
    if (wv == 2 || wv == 3) {
        #pragma unroll
        for (int u = 0; u < 4; ++u)
            #pragma unroll
            for (int r = 0; r < 4; ++r)
                ped[wv - 2][(quad * 4 + r) * 68 + u * 16 + m] = acc[u][r];
    }
    __syncthreads();
    if (wv < 2) {
        #pragma unroll
        for (int u = 0; u < 4; ++u)
            #pragma unroll
            for (int r = 0; r < 4; ++r)
                acc[u][r] += ped[wv][(quad * 4 + r) * 68 + u * 16 + m];
    }
    __syncthreads();
    if (wv == 1) {
        #pragma unroll
        for (int u = 0; u < 4; ++u)
            #pragma unroll
            for (int r = 0; r < 4; ++r)
                ped[0][(quad * 4 + r) * 68 + u * 16 + m] = acc[u][r];
    }
    __syncthreads();
    if (wv == 0) {
        #pragma unroll
        for (int u = 0; u < 4; ++u)
            #pragma unroll
            for (int r = 0; r < 4; ++r)
                ped[0][(quad * 4 + r) * 68 + u * 16 + m] += acc[u][r];
    }
    __syncthreads();
    if (tid < 256) {
        const int t = tid >> 4, kq = tid & 15;
        float4 o = *(const float4*)&ped[0][t * 68 + kq * 4];
        *(float4*)(out + (size_t)(tokbase + t) * 64 + kq * 4) = o;
    }
}

extern "C" void kernel_launch(void* const* d_in, const int* in_sizes, int n_in,
                              void* d_out, int out_size, void* d_ws, size_t ws_size,
                              hipStream_t stream) {
    const float* x   = (const float*)d_in[0];
    const float* s   = (const float*)d_in[1];
    const float* fw1 = (const float*)d_in[2];
    const float* fb1 = (const float*)d_in[3];
    const float* fw2 = (const float*)d_in[4];
    const float* fb2 = (const float*)d_in[5];
    const float* fw3 = (const float*)d_in[6];
    const float* fb3 = (const float*)d_in[7];
    const float* ew1 = (const float*)d_in[8];
    const float* eb1 = (const float*)d_in[9];
    const float* ew3 = (const float*)d_in[10];
    const float* eb3 = (const float*)d_in[11];
    float* out = (float*)d_out;

    const size_t ws_need = (size_t)65 * 4096 * sizeof(unsigned short);  // 532,480 B
    if (ws_size >= ws_need && (((uintptr_t)d_ws & 15) == 0)) {
        unsigned short* img = (unsigned short*)d_ws;
        prepass<<<dim3(65), dim3(256), 0, stream>>>(ew3, eb3, img);
        moe_main<<<dim3(NTOK / 32), dim3(512), 0, stream>>>(
            x, s, fw1, fb1, fw2, fb2, fw3, fb3, ew1, eb1, ew3, eb3, img, out);
    } else {
        moe_fb<<<dim3(NTOK / 16), dim3(512), 0, stream>>>(
            x, s, fw1, fb1, fw2, fb2, fw3, fb3, ew1, eb1, ew3, eb3, out);
    }
}

// Round 12
// 115.877 us; speedup vs baseline: 2.0767x; 1.2602x over previous
//
#include <hip/hip_runtime.h>
#include <hip/hip_bf16.h>
#include <math.h>

// B=32,T=512 -> NTOK=16384 tokens; F=64; H=64; E=32
#define NTOK 16384

typedef __attribute__((ext_vector_type(8))) short short8;   // 8 bf16 (MFMA A/B)
typedef __attribute__((ext_vector_type(4))) float f32x4;    // MFMA acc

__device__ __forceinline__ unsigned pack_bf16(float a, float b) {
    union { __hip_bfloat162 h; unsigned u; } cv;
    cv.h = __float22bfloat162_rn(make_float2(a, b));
    return cv.u;
}
__device__ __forceinline__ float eluf(float z) {
    return z > 0.0f ? z : (__expf(z) - 1.0f);
}

// ---------------- prepass: fragment-major bf16 B images ----------------
// slot f (0..63): B = ew3[f] (rows k=h, cols n); slot 64: B = eb3 (rows e, cols n)
// image[f][idx] uint4, idx = c*256 + u*64 + lane:
//   elem j of lane's short8 = B[c*32 + (lane>>4)*8 + j][u*16 + (lane&15)]
__global__ __launch_bounds__(256)
void prepass(const float* __restrict__ ew3, const float* __restrict__ eb3,
             unsigned short* __restrict__ ws) {
    __shared__ float tile[64 * 65];
    const int bid = blockIdx.x, tid = threadIdx.x;
    const float* src = (bid < 64) ? (ew3 + (size_t)bid * 4096) : eb3;

    const int r = tid >> 2, c0 = (tid & 3) * 16;
    #pragma unroll
    for (int j = 0; j < 4; ++j) {
        float4 v = *(const float4*)(src + r * 64 + c0 + j * 4);
        tile[r * 65 + c0 + j * 4 + 0] = v.x;
        tile[r * 65 + c0 + j * 4 + 1] = v.y;
        tile[r * 65 + c0 + j * 4 + 2] = v.z;
        tile[r * 65 + c0 + j * 4 + 3] = v.w;
    }
    __syncthreads();

    uint4* dst = (uint4*)(ws + (size_t)bid * 4096);
    #pragma unroll
    for (int it = 0; it < 2; ++it) {
        const int idx = tid + it * 256;
        const int c = idx >> 8, u = (idx >> 6) & 3, l = idx & 63;
        const int m = l & 15, q = (l >> 4) & 3;
        const int rb = c * 32 + q * 8, col = u * 16 + m;
        unsigned pw[4];
        #pragma unroll
        for (int p = 0; p < 4; ++p)
            pw[p] = pack_bf16(tile[(rb + 2 * p) * 65 + col],
                              tile[(rb + 2 * p + 1) * 65 + col]);
        uint4 pk; pk.x = pw[0]; pk.y = pw[1]; pk.z = pw[2]; pk.w = pw[3];
        dst[idx] = pk;
    }
}

// A-frag gen for TWO token tiles sharing expert weights.
__device__ __forceinline__ void gen_a2(const float* __restrict__ ew1,
                                       const float* __restrict__ eb1,
                                       int f, int quad,
                                       float xv0, float wt0, float xv1, float wt1,
                                       short8* a0, short8* a1) {
    #pragma unroll
    for (int c = 0; c < 2; ++c) {
        const float* w1p = ew1 + f * 64 + c * 32 + quad * 8;
        const float* b1p = eb1 + f * 64 + c * 32 + quad * 8;
        const float4 wa = *(const float4*)w1p, wb = *(const float4*)(w1p + 4);
        const float4 ba = *(const float4*)b1p, bb = *(const float4*)(b1p + 4);
        uint4 v0, v1;
        v0.x = pack_bf16(wt0 * eluf(fmaf(xv0, wa.x, ba.x)),
                         wt0 * eluf(fmaf(xv0, wa.y, ba.y)));
        v0.y = pack_bf16(wt0 * eluf(fmaf(xv0, wa.z, ba.z)),
                         wt0 * eluf(fmaf(xv0, wa.w, ba.w)));
        v0.z = pack_bf16(wt0 * eluf(fmaf(xv0, wb.x, bb.x)),
                         wt0 * eluf(fmaf(xv0, wb.y, bb.y)));
        v0.w = pack_bf16(wt0 * eluf(fmaf(xv0, wb.z, bb.z)),
                         wt0 * eluf(fmaf(xv0, wb.w, bb.w)));
        v1.x = pack_bf16(wt1 * eluf(fmaf(xv1, wa.x, ba.x)),
                         wt1 * eluf(fmaf(xv1, wa.y, ba.y)));
        v1.y = pack_bf16(wt1 * eluf(fmaf(xv1, wa.z, ba.z)),
                         wt1 * eluf(fmaf(xv1, wa.w, ba.w)));
        v1.z = pack_bf16(wt1 * eluf(fmaf(xv1, wb.x, bb.x)),
                         wt1 * eluf(fmaf(xv1, wb.y, bb.y)));
        v1.w = pack_bf16(wt1 * eluf(fmaf(xv1, wb.z, bb.z)),
                         wt1 * eluf(fmaf(xv1, wb.w, bb.w)));
        a0[c] = *(short8*)&v0;
        a1[c] = *(short8*)&v1;
    }
}

// ---------------- main kernel: 512 blocks x 512 thr (8 waves) ----------------
// block = 32 tokens; wave wv: f in [wv*8, wv*8+8), TWO 16-token M-tiles.
// R12 = exact R8 skeleton (launch_bounds(512,4), LDS 60.4 KB, VGPR free to 128)
//       + explicit cross-iteration B double-buffer: B[2][8] ping-pong, loop
//       fully unrolled so all indices are compile-time (no R10-style spill).
__global__ __launch_bounds__(512, 4)
void moe_main(const float* __restrict__ x,   const float* __restrict__ s,
              const float* __restrict__ fw1, const float* __restrict__ fb1,
              const float* __restrict__ fw2, const float* __restrict__ fb2,
              const float* __restrict__ fw3, const float* __restrict__ fb3,
              const float* __restrict__ ew1, const float* __restrict__ eb1,
              const float* __restrict__ ew3, const float* __restrict__ eb3,
              const unsigned short* __restrict__ img,
              float* __restrict__ out)
{
    __shared__ __align__(16) float xls[32 * 68];     // x tile [t][f]     8704 B
    __shared__ __align__(16) float wts[32 * 65];     // gates  [t][f]     8320 B
    __shared__ __align__(16) float egs[32 * 64];     // elu(g) [t][h]     8192 B
    __shared__ __align__(16) float ped0[4][16 * 68]; // tile0 partials   17408 B
    __shared__ __align__(16) float ped1[4][16 * 68]; // tile1 partials   17408 B

    const int tid = threadIdx.x;
    const int wv = tid >> 6, lane = tid & 63;
    const int m = tid & 15, quad = (tid >> 4) & 3;
    const int tokbase = blockIdx.x * 32;

    // ---- stage x tile: 32 rows x 16 float4 = 512 ----
    {
        const int t = tid >> 4, fq = (tid & 15) * 4;
        *(float4*)&xls[t * 68 + fq] =
            *(const float4*)(x + (size_t)(tokbase + t) * 64 + fq);
    }
    __syncthreads();

    // ---- gating: each wave -> softmax gates for its 4 tokens ----
    {
        const int t0w = wv * 4;
        const float* sw = s + (size_t)(tokbase + t0w) * 32;
        float g[4];
        const float b0 = fb1[lane] + fb2[lane];
        #pragma unroll
        for (int t = 0; t < 4; ++t) g[t] = b0;
        for (int f = 0; f < 64; f += 4) {
            const float w0 = fw1[(f + 0) * 64 + lane];
            const float w1 = fw1[(f + 1) * 64 + lane];
            const float w2 = fw1[(f + 2) * 64 + lane];
            const float w3v = fw1[(f + 3) * 64 + lane];
            #pragma unroll
            for (int t = 0; t < 4; ++t) {
                const float4 xa = *(const float4*)&xls[(t0w + t) * 68 + f];
                g[t] = fmaf(xa.x, w0, fmaf(xa.y, w1, fmaf(xa.z, w2, fmaf(xa.w, w3v, g[t]))));
            }
        }
        for (int e = 0; e < 32; e += 4) {
            const float w0 = fw2[(e + 0) * 64 + lane];
            const float w1 = fw2[(e + 1) * 64 + lane];
            const float w2 = fw2[(e + 2) * 64 + lane];
            const float w3v = fw2[(e + 3) * 64 + lane];
            #pragma unroll
            for (int t = 0; t < 4; ++t) {
                const float4 sa = *(const float4*)(sw + t * 32 + e);
                g[t] = fmaf(sa.x, w0, fmaf(sa.y, w1, fmaf(sa.z, w2, fmaf(sa.w, w3v, g[t]))));
            }
        }
        // egs rows are wave-private -> in-wave lgkmcnt ordering suffices
        #pragma unroll
        for (int t = 0; t < 4; ++t) egs[(t0w + t) * 64 + lane] = eluf(g[t]);

        float lg[4];
        const float b3 = fb3[lane];
        #pragma unroll
        for (int t = 0; t < 4; ++t) lg[t] = b3;
        for (int h = 0; h < 64; h += 4) {
            const float w0 = fw3[(h + 0) * 64 + lane];
            const float w1 = fw3[(h + 1) * 64 + lane];
            const float w2 = fw3[(h + 2) * 64 + lane];
            const float w3v = fw3[(h + 3) * 64 + lane];
            #pragma unroll
            for (int t = 0; t < 4; ++t) {
                const float4 ev = *(const float4*)&egs[(t0w + t) * 64 + h];
                lg[t] = fmaf(ev.x, w0, fmaf(ev.y, w1, fmaf(ev.z, w2, fmaf(ev.w, w3v, lg[t]))));
            }
        }
        #pragma unroll
        for (int t = 0; t < 4; ++t) {
            float mx = lg[t];
            #pragma unroll
            for (int off = 32; off > 0; off >>= 1) mx = fmaxf(mx, __shfl_xor(mx, off));
            const float p = __expf(lg[t] - mx);
            float sm = p;
            #pragma unroll
            for (int off = 32; off > 0; off >>= 1) sm += __shfl_xor(sm, off);
            wts[(t0w + t) * 65 + lane] = p / sm;
        }
    }
    __syncthreads();

    // ---- f-loop: 8 iters fully unrolled; B double-buffered across iters ----
    const int f0 = wv * 8;
    f32x4 acc0[4], acc1[4];
    #pragma unroll
    for (int u = 0; u < 4; ++u) {
        acc0[u] = (f32x4){0.f, 0.f, 0.f, 0.f};
        acc1[u] = (f32x4){0.f, 0.f, 0.f, 0.f};
    }

    const uint4* bp = (const uint4*)img + (size_t)f0 * 512 + lane;
    uint4 B[2][8];
    // prologue: load iter-0's fragments into buffer 0
    #pragma unroll
    for (int i = 0; i < 8; ++i) B[0][i] = bp[(i >> 2) * 256 + (i & 3) * 64];
    bp += 512;

    #pragma unroll
    for (int ff = 0; ff < 8; ++ff) {
        const int f = f0 + ff;
        const int cur = ff & 1, nxt = cur ^ 1;   // compile-time under full unroll
        // 1) prefetch NEXT iteration's B-fragments (fly under this iter's work)
        if (ff < 7) {
            #pragma unroll
            for (int i = 0; i < 8; ++i) B[nxt][i] = bp[(i >> 2) * 256 + (i & 3) * 64];
            bp += 512;
        }
        // 2) A-gen for both tiles
        const float xv0 = xls[m * 68 + f];
        const float wt0 = wts[m * 65 + f];
        const float xv1 = xls[(16 + m) * 68 + f];
        const float wt1 = wts[(16 + m) * 65 + f];
        short8 a0[2], a1[2];
        gen_a2(ew1, eb1, f, quad, xv0, wt0, xv1, wt1, a0, a1);
        // 3) 16 MFMA on the CURRENT buffer (loaded a full iteration ago)
        acc0[0] = __builtin_amdgcn_mfma_f32_16x16x32_bf16(a0[0], *(short8*)&B[cur][0], acc0[0], 0, 0, 0);
        acc0[1] = __builtin_amdgcn_mfma_f32_16x16x32_bf16(a0[0], *(short8*)&B[cur][1], acc0[1], 0, 0, 0);
        acc0[2] = __builtin_amdgcn_mfma_f32_16x16x32_bf16(a0[0], *(short8*)&B[cur][2], acc0[2], 0, 0, 0);
        acc0[3] = __builtin_amdgcn_mfma_f32_16x16x32_bf16(a0[0], *(short8*)&B[cur][3], acc0[3], 0, 0, 0);
        acc1[0] = __builtin_amdgcn_mfma_f32_16x16x32_bf16(a1[0], *(short8*)&B[cur][0], acc1[0], 0, 0, 0);
        acc1[1] = __builtin_amdgcn_mfma_f32_16x16x32_bf16(a1[0], *(short8*)&B[cur][1], acc1[1], 0, 0, 0);
        acc1[2] = __builtin_amdgcn_mfma_f32_16x16x32_bf16(a1[0], *(short8*)&B[cur][2], acc1[2], 0, 0, 0);
        acc1[3] = __builtin_amdgcn_mfma_f32_16x16x32_bf16(a1[0], *(short8*)&B[cur][3], acc1[3], 0, 0, 0);
        acc0[0] = __builtin_amdgcn_mfma_f32_16x16x32_bf16(a0[1], *(short8*)&B[cur][4], acc0[0], 0, 0, 0);
        acc0[1] = __builtin_amdgcn_mfma_f32_16x16x32_bf16(a0[1], *(short8*)&B[cur][5], acc0[1], 0, 0, 0);
        acc0[2] = __builtin_amdgcn_mfma_f32_16x16x32_bf16(a0[1], *(short8*)&B[cur][6], acc0[2], 0, 0, 0);
        acc0[3] = __builtin_amdgcn_mfma_f32_16x16x32_bf16(a0[1], *(short8*)&B[cur][7], acc0[3], 0, 0, 0);
        acc1[0] = __builtin_amdgcn_mfma_f32_16x16x32_bf16(a1[1], *(short8*)&B[cur][4], acc1[0], 0, 0, 0);
        acc1[1] = __builtin_amdgcn_mfma_f32_16x16x32_bf16(a1[1], *(short8*)&B[cur][5], acc1[1], 0, 0, 0);
        acc1[2] = __builtin_amdgcn_mfma_f32_16x16x32_bf16(a1[1], *(short8*)&B[cur][6], acc1[2], 0, 0, 0);
        acc1[3] = __builtin_amdgcn_mfma_f32_16x16x32_bf16(a1[1], *(short8*)&B[cur][7], acc1[3], 0, 0, 0);
    }

    // ---- bias K-chunk: waves 0..3 = {tile} x {e-half} ----
    if (wv < 4) {
        const int tile = wv >> 1, eh = wv & 1;
        const int e0 = eh * 32 + quad * 8;
        const int trow = tile * 16 + m;
        uint4 av;
        av.x = pack_bf16(wts[trow * 65 + e0 + 0], wts[trow * 65 + e0 + 1]);
        av.y = pack_bf16(wts[trow * 65 + e0 + 2], wts[trow * 65 + e0 + 3]);
        av.z = pack_bf16(wts[trow * 65 + e0 + 4], wts[trow * 65 + e0 + 5]);
        av.w = pack_bf16(wts[trow * 65 + e0 + 6], wts[trow * 65 + e0 + 7]);
        short8 a = *(short8*)&av;
        const uint4* bq = (const uint4*)img + (size_t)64 * 512;
        if (tile == 0) {
            #pragma unroll
            for (int u = 0; u < 4; ++u) {
                uint4 bv = bq[eh * 256 + u * 64 + lane];
                acc0[u] = __builtin_amdgcn_mfma_f32_16x16x32_bf16(a, *(short8*)&bv, acc0[u], 0, 0, 0);
            }
        } else {
            #pragma unroll
            for (int u = 0; u < 4; ++u) {
                uint4 bv = bq[eh * 256 + u * 64 + lane];
                acc1[u] = __builtin_amdgcn_mfma_f32_16x16x32_bf16(a, *(short8*)&bv, acc1[u], 0, 0, 0);
            }
        }
    }

    // ---- tree reduction over 8 wave-partials, both tiles in parallel ----
    // (C layout: row = quad*4+r, col = u*16+m)
    if (wv >= 4) {
        #pragma unroll
        for (int u = 0; u < 4; ++u)
            #pragma unroll
            for (int r = 0; r < 4; ++r) {
                const int idx = (quad * 4 + r) * 68 + u * 16 + m;
                ped0[wv - 4][idx] = acc0[u][r];
                ped1[wv - 4][idx] = acc1[u][r];
            }
    }
    __syncthreads();
    if (wv < 4) {
        #pragma unroll
        for (int u = 0; u < 4; ++u)
            #pragma unroll
            for (int r = 0; r < 4; ++r) {
                const int idx = (quad * 4 + r) * 68 + u * 16 + m;
                acc0[u][r] += ped0[wv][idx];
                acc1[u][r] += ped1[wv][idx];
            }
    }
    __syncthreads();
    if (wv == 2 || wv == 3) {
        #pragma unroll
        for (int u = 0; u < 4; ++u)
            #pragma unroll
            for (int r = 0; r < 4; ++r) {
                const int idx = (quad * 4 + r) * 68 + u * 16 + m;
                ped0[wv - 2][idx] = acc0[u][r];
                ped1[wv - 2][idx] = acc1[u][r];
            }
    }
    __syncthreads();
    if (wv < 2) {
        #pragma unroll
        for (int u = 0; u < 4; ++u)
            #pragma unroll
            for (int r = 0; r < 4; ++r) {
                const int idx = (quad * 4 + r) * 68 + u * 16 + m;
                acc0[u][r] += ped0[wv][idx];
                acc1[u][r] += ped1[wv][idx];
            }
    }
    __syncthreads();
    if (wv == 1) {
        #pragma unroll
        for (int u = 0; u < 4; ++u)
            #pragma unroll
            for (int r = 0; r < 4; ++r) {
                const int idx = (quad * 4 + r) * 68 + u * 16 + m;
                ped0[0][idx] = acc0[u][r];
                ped1[0][idx] = acc1[u][r];
            }
    }
    __syncthreads();
    if (wv == 0) {
        #pragma unroll
        for (int u = 0; u < 4; ++u)
            #pragma unroll
            for (int r = 0; r < 4; ++r) {
                const int idx = (quad * 4 + r) * 68 + u * 16 + m;
                ped0[0][idx] += acc0[u][r];
                ped1[0][idx] += acc1[u][r];
            }
    }
    __syncthreads();

    // ---- final store: 32 tokens x 16 float4, coalesced ----
    {
        const int t = tid >> 4, kq = tid & 15;
        const float* srcp = (t < 16) ? &ped0[0][t * 68 + kq * 4]
                                     : &ped1[0][(t - 16) * 68 + kq * 4];
        *(float4*)(out + (size_t)(tokbase + t) * 64 + kq * 4) = *(const float4*)srcp;
    }
}

// ======================================================================
// Fallback (ws-free), validated structure: 1024 blocks x 512 thr, 16 tok
// ======================================================================
__device__ __forceinline__ void gen_a_fb(const float* __restrict__ ew1,
                                         const float* __restrict__ eb1,
                                         int f, int quad, float xv, float wt,
                                         short8* a) {
    #pragma unroll
    for (int c = 0; c < 2; ++c) {
        const float* w1p = ew1 + f * 64 + c * 32 + quad * 8;
        const float* b1p = eb1 + f * 64 + c * 32 + quad * 8;
        const float4 w1a = *(const float4*)w1p, w1b = *(const float4*)(w1p + 4);
        const float4 b1a = *(const float4*)b1p, b1b = *(const float4*)(b1p + 4);
        uint4 av;
        av.x = pack_bf16(wt * eluf(fmaf(xv, w1a.x, b1a.x)),
                         wt * eluf(fmaf(xv, w1a.y, b1a.y)));
        av.y = pack_bf16(wt * eluf(fmaf(xv, w1a.z, b1a.z)),
                         wt * eluf(fmaf(xv, w1a.w, b1a.w)));
        av.z = pack_bf16(wt * eluf(fmaf(xv, w1b.x, b1b.x)),
                         wt * eluf(fmaf(xv, w1b.y, b1b.y)));
        av.w = pack_bf16(wt * eluf(fmaf(xv, w1b.z, b1b.z)),
                         wt * eluf(fmaf(xv, w1b.w, b1b.w)));
        a[c] = *(short8*)&av;
    }
}
__device__ __forceinline__ void gen_b_fp32(const float* __restrict__ w3f,
                                           int quad, int m, short8 b[2][4]) {
    #pragma unroll
    for (int c = 0; c < 2; ++c)
        #pragma unroll
        for (int u = 0; u < 4; ++u) {
            const float* wp = w3f + (size_t)(c * 32 + quad * 8) * 64 + u * 16 + m;
            uint4 v;
            v.x = pack_bf16(wp[0],   wp[64]);
            v.y = pack_bf16(wp[128], wp[192]);
            v.z = pack_bf16(wp[256], wp[320]);
            v.w = pack_bf16(wp[384], wp[448]);
            b[c][u] = *(short8*)&v;
        }
}

__global__ __launch_bounds__(512, 8)
void moe_fb(const float* __restrict__ x,   const float* __restrict__ s,
            const float* __restrict__ fw1, const float* __restrict__ fb1,
            const float* __restrict__ fw2, const float* __restrict__ fb2,
            const float* __restrict__ fw3, const float* __restrict__ fb3,
            const float* __restrict__ ew1, const float* __restrict__ eb1,
            const float* __restrict__ ew3, const float* __restrict__ eb3,
            float* __restrict__ out)
{
    __shared__ __align__(16) float xls[16 * 68];
    __shared__ __align__(16) float wts[16 * 65];
    __shared__ __align__(16) float egs[16 * 64];
    __shared__ __align__(16) float ped[4][16 * 68];

    const int tid = threadIdx.x;
    const int wv = tid >> 6, lane = tid & 63;
    const int tokbase = blockIdx.x * 16;

    if (tid < 256) {
        const int t = tid >> 4, fq = (tid & 15) * 4;
        *(float4*)&xls[t * 68 + fq] =
            *(const float4*)(x + (size_t)(tokbase + t) * 64 + fq);
    }
    __syncthreads();
    {
        const int t0w = wv * 2;
        const float* sw = s + (size_t)(tokbase + t0w) * 32;
        float g0, g1;
        g0 = g1 = fb1[lane] + fb2[lane];
        for (int ff = 0; ff < 64; ff += 4) {
            const float4 xa = *(const float4*)&xls[(t0w + 0) * 68 + ff];
            const float4 xb = *(const float4*)&xls[(t0w + 1) * 68 + ff];
            const float w0 = fw1[(ff + 0) * 64 + lane];
            const float w1 = fw1[(ff + 1) * 64 + lane];
            const float w2 = fw1[(ff + 2) * 64 + lane];
            const float w3v = fw1[(ff + 3) * 64 + lane];
            g0 = fmaf(xa.x, w0, fmaf(xa.y, w1, fmaf(xa.z, w2, fmaf(xa.w, w3v, g0))));
            g1 = fmaf(xb.x, w0, fmaf(xb.y, w1, fmaf(xb.z, w2, fmaf(xb.w, w3v, g1))));
        }
        for (int e = 0; e < 32; e += 4) {
            const float4 sa = *(const float4*)(sw + e);
            const float4 sb = *(const float4*)(sw + 32 + e);
            const float w0 = fw2[(e + 0) * 64 + lane];
            const float w1 = fw2[(e + 1) * 64 + lane];
            const float w2 = fw2[(e + 2) * 64 + lane];
            const float w3v = fw2[(e + 3) * 64 + lane];
            g0 = fmaf(sa.x, w0, fmaf(sa.y, w1, fmaf(sa.z, w2, fmaf(sa.w, w3v, g0))));
            g1 = fmaf(sb.x, w0, fmaf(sb.y, w1, fmaf(sb.z, w2, fmaf(sb.w, w3v, g1))));
        }
        egs[(t0w + 0) * 64 + lane] = eluf(g0);
        egs[(t0w + 1) * 64 + lane] = eluf(g1);
        float lg0 = fb3[lane], lg1 = lg0;
        for (int h = 0; h < 64; h += 4) {
            const float4 e0 = *(const float4*)&egs[(t0w + 0) * 64 + h];
            const float4 e1 = *(const float4*)&egs[(t0w + 1) * 64 + h];
            const float w0 = fw3[(h + 0) * 64 + lane];
            const float w1 = fw3[(h + 1) * 64 + lane];
            const float w2 = fw3[(h + 2) * 64 + lane];
            const float w3v = fw3[(h + 3) * 64 + lane];
            lg0 = fmaf(e0.x, w0, fmaf(e0.y, w1, fmaf(e0.z, w2, fmaf(e0.w, w3v, lg0))));
            lg1 = fmaf(e1.x, w0, fmaf(e1.y, w1, fmaf(e1.z, w2, fmaf(e1.w, w3v, lg1))));
        }
        float mx0 = lg0, mx1 = lg1;
        #pragma unroll
        for (int off = 32; off > 0; off >>= 1) {
            mx0 = fmaxf(mx0, __shfl_xor(mx0, off));
            mx1 = fmaxf(mx1, __shfl_xor(mx1, off));
        }
        const float p0 = __expf(lg0 - mx0), p1 = __expf(lg1 - mx1);
        float s0 = p0, s1 = p1;
        #pragma unroll
        for (int off = 32; off > 0; off >>= 1) {
            s0 += __shfl_xor(s0, off);
            s1 += __shfl_xor(s1, off);
        }
        wts[(t0w + 0) * 65 + lane] = p0 / s0;
        wts[(t0w + 1) * 65 + lane] = p1 / s1;
    }
    __syncthreads();

    const int m = tid & 15, quad = (tid >> 4) & 3;
    const int f0 = wv * 8;
    f32x4 acc[4];
    #pragma unroll
    for (int u = 0; u < 4; ++u) acc[u] = (f32x4){0.f, 0.f, 0.f, 0.f};

    #pragma unroll
    for (int ff = 0; ff < 8; ++ff) {
        const int fcur = f0 + ff;
        short8 b[2][4], a[2];
        gen_b_fp32(ew3 + (size_t)fcur * 4096, quad, m, b);
        gen_a_fb(ew1, eb1, fcur, quad, xls[m * 68 + fcur], wts[m * 65 + fcur], a);
        #pragma unroll
        for (int u = 0; u < 4; ++u) {
            acc[u] = __builtin_amdgcn_mfma_f32_16x16x32_bf16(a[0], b[0][u], acc[u], 0, 0, 0);
            acc[u] = __builtin_amdgcn_mfma_f32_16x16x32_bf16(a[1], b[1][u], acc[u], 0, 0, 0);
        }
    }
    if (wv < 2) {
        const int e0 = wv * 32 + quad * 8;
        uint4 av;
        av.x = pack_bf16(wts[m * 65 + e0 + 0], wts[m * 65 + e0 + 1]);
        av.y = pack_bf16(wts[m * 65 + e0 + 2], wts[m * 65 + e0 + 3]);
        av.z = pack_bf16(wts[m * 65 + e0 + 4], wts[m * 65 + e0 + 5]);
        av.w = pack_bf16(wts[m * 65 + e0 + 6], wts[m * 65 + e0 + 7]);
        short8 a = *(short8*)&av;
        #pragma unroll
        for (int u = 0; u < 4; ++u) {
            const float* wp = eb3 + (size_t)e0 * 64 + u * 16 + m;
            uint4 bv;
            bv.x = pack_bf16(wp[0],   wp[64]);
            bv.y = pack_bf16(wp[128], wp[192]);
            bv.z = pack_bf16(wp[256], wp[320]);
            bv.w = pack_bf16(wp[384], wp[448]);
            acc[u] = __builtin_amdgcn_mfma_f32_16x16x32_bf16(a, *(short8*)&bv, acc[u], 0, 0, 0);
        }
    }
    if (wv >= 4) {
        #pragma unroll
        for (int u = 0; u < 4; ++u)
            #pragma unroll
            for (int r = 0; r < 4; ++r)
                ped[wv - 4][(quad * 4 + r) * 68 + u * 16 + m] = acc[u][r];
    }
    __syncthreads();
    if (wv < 4) {
        #pragma unroll
        for (int u = 0; u < 4; ++u)
            #pragma unroll
            for (int r = 0; r < 4; ++r)
                acc[u][r] += ped[wv][(quad * 4 + r) * 68 + u * 16 + m];
    }
    __syncthreads();
    if (wv == 2 || wv == 3) {
        #pragma unroll
        for (int u = 0; u < 4; ++u)
            #pragma unroll
            for (int r = 0; r < 4; ++r)
                ped[wv - 2][(quad * 4 + r) * 68 + u * 16 + m] = acc[u][r];
    }
    __syncthreads();
    if (wv < 2) {
        #pragma unroll
        for (int u = 0; u < 4; ++u)
            #pragma unroll
            for (int r = 0; r < 4; ++r)
                acc[u][r] += ped[wv][(quad * 4 + r) * 68 + u * 16 + m];
    }
    __syncthreads();
    if (wv == 1) {
        #pragma unroll
        for (int u = 0; u < 4; ++u)
            #pragma unroll
            for (int r = 0; r < 4; ++r)
                ped[0][(quad * 4 + r) * 68 + u * 16 + m] = acc[u][r];
    }
    __syncthreads();
    if (wv == 0) {
        #pragma unroll
        for (int u = 0; u < 4; ++u)
            #pragma unroll
            for (int r = 0; r < 4; ++r)
                ped[0][(quad * 4 + r) * 68 + u * 16 + m] += acc[u][r];
    }
    __syncthreads();
    if (tid < 256) {
        const int t = tid >> 4, kq = tid & 15;
        float4 o = *(const float4*)&ped[0][t * 68 + kq * 4];
        *(float4*)(out + (size_t)(tokbase + t) * 64 + kq * 4) = o;
    }
}

extern "C" void kernel_launch(void* const* d_in, const int* in_sizes, int n_in,
                              void* d_out, int out_size, void* d_ws, size_t ws_size,
                              hipStream_t stream) {
    const float* x   = (const float*)d_in[0];
    const float* s   = (const float*)d_in[1];
    const float* fw1 = (const float*)d_in[2];
    const float* fb1 = (const float*)d_in[3];
    const float* fw2 = (const float*)d_in[4];
    const float* fb2 = (const float*)d_in[5];
    const float* fw3 = (const float*)d_in[6];
    const float* fb3 = (const float*)d_in[7];
    const float* ew1 = (const float*)d_in[8];
    const float* eb1 = (const float*)d_in[9];
    const float* ew3 = (const float*)d_in[10];
    const float* eb3 = (const float*)d_in[11];
    float* out = (float*)d_out;

    const size_t ws_need = (size_t)65 * 4096 * sizeof(unsigned short);  // 532,480 B
    if (ws_size >= ws_need && (((uintptr_t)d_ws & 15) == 0)) {
        unsigned short* img = (unsigned short*)d_ws;
        prepass<<<dim3(65), dim3(256), 0, stream>>>(ew3, eb3, img);
        moe_main<<<dim3(NTOK / 32), dim3(512), 0, stream>>>(
            x, s, fw1, fb1, fw2, fb2, fw3, fb3, ew1, eb1, ew3, eb3, img, out);
    } else {
        moe_fb<<<dim3(NTOK / 16), dim3(512), 0, stream>>>(
            x, s, fw1, fb1, fw2, fb2, fw3, fb3, ew1, eb1, ew3, eb3, out);
    }
}

// Round 13
// 114.827 us; speedup vs baseline: 2.0956x; 1.0091x over previous
//
#include <hip/hip_runtime.h>
#include <hip/hip_bf16.h>
#include <math.h>

// B=32,T=512 -> NTOK=16384 tokens; F=64; H=64; E=32
#define NTOK 16384

typedef __attribute__((ext_vector_type(8))) short short8;   // 8 bf16 (MFMA A/B)
typedef __attribute__((ext_vector_type(4))) float f32x4;    // MFMA acc

__device__ __forceinline__ unsigned pack_bf16(float a, float b) {
    union { __hip_bfloat162 h; unsigned u; } cv;
    cv.h = __float22bfloat162_rn(make_float2(a, b));
    return cv.u;
}
__device__ __forceinline__ float eluf(float z) {
    return z > 0.0f ? z : (__expf(z) - 1.0f);
}

// ---------------- prepass: fragment-major bf16 B images ----------------
// slot f (0..63): B = ew3[f] (rows k=h, cols n); slot 64: B = eb3 (rows e, cols n)
// image[f][idx] uint4, idx = c*256 + u*64 + lane:
//   elem j of lane's short8 = B[c*32 + (lane>>4)*8 + j][u*16 + (lane&15)]
__global__ __launch_bounds__(256)
void prepass(const float* __restrict__ ew3, const float* __restrict__ eb3,
             unsigned short* __restrict__ ws) {
    __shared__ float tile[64 * 65];
    const int bid = blockIdx.x, tid = threadIdx.x;
    const float* src = (bid < 64) ? (ew3 + (size_t)bid * 4096) : eb3;

    const int r = tid >> 2, c0 = (tid & 3) * 16;
    #pragma unroll
    for (int j = 0; j < 4; ++j) {
        float4 v = *(const float4*)(src + r * 64 + c0 + j * 4);
        tile[r * 65 + c0 + j * 4 + 0] = v.x;
        tile[r * 65 + c0 + j * 4 + 1] = v.y;
        tile[r * 65 + c0 + j * 4 + 2] = v.z;
        tile[r * 65 + c0 + j * 4 + 3] = v.w;
    }
    __syncthreads();

    uint4* dst = (uint4*)(ws + (size_t)bid * 4096);
    #pragma unroll
    for (int it = 0; it < 2; ++it) {
        const int idx = tid + it * 256;
        const int c = idx >> 8, u = (idx >> 6) & 3, l = idx & 63;
        const int m = l & 15, q = (l >> 4) & 3;
        const int rb = c * 32 + q * 8, col = u * 16 + m;
        unsigned pw[4];
        #pragma unroll
        for (int p = 0; p < 4; ++p)
            pw[p] = pack_bf16(tile[(rb + 2 * p) * 65 + col],
                              tile[(rb + 2 * p + 1) * 65 + col]);
        uint4 pk; pk.x = pw[0]; pk.y = pw[1]; pk.z = pw[2]; pk.w = pw[3];
        dst[idx] = pk;
    }
}

// ---------------- main kernel: 512 blocks x 512 thr (8 waves) ----------------
// block = 32 tokens; wave wv: f in [wv*8, wv*8+8), TWO 16-token M-tiles.
// R13 = R12 + FULL cross-iteration prefetch: B-frags AND ew1/eb1 float4s AND
// the xls/wts scalars all ping-pong one iteration ahead, so no memory latency
// sits in the A-gen->MFMA dependency chain (except iter 0's prologue).
// All ping-pong indices compile-time under full unroll (no dynamic indexing).
__global__ __launch_bounds__(512, 4)
void moe_main(const float* __restrict__ x,   const float* __restrict__ s,
              const float* __restrict__ fw1, const float* __restrict__ fb1,
              const float* __restrict__ fw2, const float* __restrict__ fb2,
              const float* __restrict__ fw3, const float* __restrict__ fb3,
              const float* __restrict__ ew1, const float* __restrict__ eb1,
              const float* __restrict__ ew3, const float* __restrict__ eb3,
              const unsigned short* __restrict__ img,
              float* __restrict__ out)
{
    __shared__ __align__(16) float xls[32 * 68];     // x tile [t][f]     8704 B
    __shared__ __align__(16) float wts[32 * 65];     // gates  [t][f]     8320 B
    __shared__ __align__(16) float egs[32 * 64];     // elu(g) [t][h]     8192 B
    __shared__ __align__(16) float ped0[4][16 * 68]; // tile0 partials   17408 B
    __shared__ __align__(16) float ped1[4][16 * 68]; // tile1 partials   17408 B

    const int tid = threadIdx.x;
    const int wv = tid >> 6, lane = tid & 63;
    const int m = tid & 15, quad = (tid >> 4) & 3;
    const int tokbase = blockIdx.x * 32;

    // ---- stage x tile: 32 rows x 16 float4 = 512 ----
    {
        const int t = tid >> 4, fq = (tid & 15) * 4;
        *(float4*)&xls[t * 68 + fq] =
            *(const float4*)(x + (size_t)(tokbase + t) * 64 + fq);
    }
    __syncthreads();

    // ---- gating: each wave -> softmax gates for its 4 tokens ----
    {
        const int t0w = wv * 4;
        const float* sw = s + (size_t)(tokbase + t0w) * 32;
        float g[4];
        const float b0 = fb1[lane] + fb2[lane];
        #pragma unroll
        for (int t = 0; t < 4; ++t) g[t] = b0;
        for (int f = 0; f < 64; f += 4) {
            const float w0 = fw1[(f + 0) * 64 + lane];
            const float w1 = fw1[(f + 1) * 64 + lane];
            const float w2 = fw1[(f + 2) * 64 + lane];
            const float w3v = fw1[(f + 3) * 64 + lane];
            #pragma unroll
            for (int t = 0; t < 4; ++t) {
                const float4 xa = *(const float4*)&xls[(t0w + t) * 68 + f];
                g[t] = fmaf(xa.x, w0, fmaf(xa.y, w1, fmaf(xa.z, w2, fmaf(xa.w, w3v, g[t]))));
            }
        }
        for (int e = 0; e < 32; e += 4) {
            const float w0 = fw2[(e + 0) * 64 + lane];
            const float w1 = fw2[(e + 1) * 64 + lane];
            const float w2 = fw2[(e + 2) * 64 + lane];
            const float w3v = fw2[(e + 3) * 64 + lane];
            #pragma unroll
            for (int t = 0; t < 4; ++t) {
                const float4 sa = *(const float4*)(sw + t * 32 + e);
                g[t] = fmaf(sa.x, w0, fmaf(sa.y, w1, fmaf(sa.z, w2, fmaf(sa.w, w3v, g[t]))));
            }
        }
        // egs rows are wave-private -> in-wave lgkmcnt ordering suffices
        #pragma unroll
        for (int t = 0; t < 4; ++t) egs[(t0w + t) * 64 + lane] = eluf(g[t]);

        float lg[4];
        const float b3 = fb3[lane];
        #pragma unroll
        for (int t = 0; t < 4; ++t) lg[t] = b3;
        for (int h = 0; h < 64; h += 4) {
            const float w0 = fw3[(h + 0) * 64 + lane];
            const float w1 = fw3[(h + 1) * 64 + lane];
            const float w2 = fw3[(h + 2) * 64 + lane];
            const float w3v = fw3[(h + 3) * 64 + lane];
            #pragma unroll
            for (int t = 0; t < 4; ++t) {
                const float4 ev = *(const float4*)&egs[(t0w + t) * 64 + h];
                lg[t] = fmaf(ev.x, w0, fmaf(ev.y, w1, fmaf(ev.z, w2, fmaf(ev.w, w3v, lg[t]))));
            }
        }
        #pragma unroll
        for (int t = 0; t < 4; ++t) {
            float mx = lg[t];
            #pragma unroll
            for (int off = 32; off > 0; off >>= 1) mx = fmaxf(mx, __shfl_xor(mx, off));
            const float p = __expf(lg[t] - mx);
            float sm = p;
            #pragma unroll
            for (int off = 32; off > 0; off >>= 1) sm += __shfl_xor(sm, off);
            wts[(t0w + t) * 65 + lane] = p / sm;
        }
    }
    __syncthreads();

    // ---- f-loop: 8 iters fully unrolled; EVERYTHING double-buffered ----
    const int f0 = wv * 8;
    f32x4 acc0[4], acc1[4];
    #pragma unroll
    for (int u = 0; u < 4; ++u) {
        acc0[u] = (f32x4){0.f, 0.f, 0.f, 0.f};
        acc1[u] = (f32x4){0.f, 0.f, 0.f, 0.f};
    }

    const uint4* bp = (const uint4*)img + (size_t)f0 * 512 + lane;
    uint4  B[2][8];      // B-fragments ping-pong
    float4 W[2][4];      // ew1 float4s: [buf][c*2+half]
    float4 Bb[2][4];     // eb1 float4s
    float  XV[2][2];     // x scalar per tile
    float  WT[2][2];     // gate scalar per tile

    // prologue: load iteration 0's full input set into buffer 0
    #pragma unroll
    for (int i = 0; i < 8; ++i) B[0][i] = bp[(i >> 2) * 256 + (i & 3) * 64];
    bp += 512;
    #pragma unroll
    for (int c = 0; c < 2; ++c) {
        W[0][c * 2 + 0]  = *(const float4*)(ew1 + f0 * 64 + c * 32 + quad * 8);
        W[0][c * 2 + 1]  = *(const float4*)(ew1 + f0 * 64 + c * 32 + quad * 8 + 4);
        Bb[0][c * 2 + 0] = *(const float4*)(eb1 + f0 * 64 + c * 32 + quad * 8);
        Bb[0][c * 2 + 1] = *(const float4*)(eb1 + f0 * 64 + c * 32 + quad * 8 + 4);
    }
    XV[0][0] = xls[m * 68 + f0];        WT[0][0] = wts[m * 65 + f0];
    XV[0][1] = xls[(16 + m) * 68 + f0]; WT[0][1] = wts[(16 + m) * 65 + f0];

    #pragma unroll
    for (int ff = 0; ff < 8; ++ff) {
        const int cur = ff & 1, nxt = cur ^ 1;   // compile-time under full unroll
        // 1) prefetch EVERYTHING for iteration ff+1
        if (ff < 7) {
            const int fn = f0 + ff + 1;
            #pragma unroll
            for (int i = 0; i < 8; ++i) B[nxt][i] = bp[(i >> 2) * 256 + (i & 3) * 64];
            bp += 512;
            #pragma unroll
            for (int c = 0; c < 2; ++c) {
                W[nxt][c * 2 + 0]  = *(const float4*)(ew1 + fn * 64 + c * 32 + quad * 8);
                W[nxt][c * 2 + 1]  = *(const float4*)(ew1 + fn * 64 + c * 32 + quad * 8 + 4);
                Bb[nxt][c * 2 + 0] = *(const float4*)(eb1 + fn * 64 + c * 32 + quad * 8);
                Bb[nxt][c * 2 + 1] = *(const float4*)(eb1 + fn * 64 + c * 32 + quad * 8 + 4);
            }
            XV[nxt][0] = xls[m * 68 + fn];        WT[nxt][0] = wts[m * 65 + fn];
            XV[nxt][1] = xls[(16 + m) * 68 + fn]; WT[nxt][1] = wts[(16 + m) * 65 + fn];
        }
        // 2) A-gen from registers only (no in-chain memory latency)
        const float xv0 = XV[cur][0], wt0 = WT[cur][0];
        const float xv1 = XV[cur][1], wt1 = WT[cur][1];
        short8 a0[2], a1[2];
        #pragma unroll
        for (int c = 0; c < 2; ++c) {
            const float4 wa = W[cur][c * 2 + 0],  wb = W[cur][c * 2 + 1];
            const float4 ba = Bb[cur][c * 2 + 0], bb = Bb[cur][c * 2 + 1];
            uint4 v0, v1;
            v0.x = pack_bf16(wt0 * eluf(fmaf(xv0, wa.x, ba.x)),
                             wt0 * eluf(fmaf(xv0, wa.y, ba.y)));
            v0.y = pack_bf16(wt0 * eluf(fmaf(xv0, wa.z, ba.z)),
                             wt0 * eluf(fmaf(xv0, wa.w, ba.w)));
            v0.z = pack_bf16(wt0 * eluf(fmaf(xv0, wb.x, bb.x)),
                             wt0 * eluf(fmaf(xv0, wb.y, bb.y)));
            v0.w = pack_bf16(wt0 * eluf(fmaf(xv0, wb.z, bb.z)),
                             wt0 * eluf(fmaf(xv0, wb.w, bb.w)));
            v1.x = pack_bf16(wt1 * eluf(fmaf(xv1, wa.x, ba.x)),
                             wt1 * eluf(fmaf(xv1, wa.y, ba.y)));
            v1.y = pack_bf16(wt1 * eluf(fmaf(xv1, wa.z, ba.z)),
                             wt1 * eluf(fmaf(xv1, wa.w, ba.w)));
            v1.z = pack_bf16(wt1 * eluf(fmaf(xv1, wb.x, bb.x)),
                             wt1 * eluf(fmaf(xv1, wb.y, bb.y)));
            v1.w = pack_bf16(wt1 * eluf(fmaf(xv1, wb.z, bb.z)),
                             wt1 * eluf(fmaf(xv1, wb.w, bb.w)));
            a0[c] = *(short8*)&v0;
            a1[c] = *(short8*)&v1;
        }
        // 3) 16 MFMA on the CURRENT buffer (loaded a full iteration ago)
        acc0[0] = __builtin_amdgcn_mfma_f32_16x16x32_bf16(a0[0], *(short8*)&B[cur][0], acc0[0], 0, 0, 0);
        acc0[1] = __builtin_amdgcn_mfma_f32_16x16x32_bf16(a0[0], *(short8*)&B[cur][1], acc0[1], 0, 0, 0);
        acc0[2] = __builtin_amdgcn_mfma_f32_16x16x32_bf16(a0[0], *(short8*)&B[cur][2], acc0[2], 0, 0, 0);
        acc0[3] = __builtin_amdgcn_mfma_f32_16x16x32_bf16(a0[0], *(short8*)&B[cur][3], acc0[3], 0, 0, 0);
        acc1[0] = __builtin_amdgcn_mfma_f32_16x16x32_bf16(a1[0], *(short8*)&B[cur][0], acc1[0], 0, 0, 0);
        acc1[1] = __builtin_amdgcn_mfma_f32_16x16x32_bf16(a1[0], *(short8*)&B[cur][1], acc1[1], 0, 0, 0);
        acc1[2] = __builtin_amdgcn_mfma_f32_16x16x32_bf16(a1[0], *(short8*)&B[cur][2], acc1[2], 0, 0, 0);
        acc1[3] = __builtin_amdgcn_mfma_f32_16x16x32_bf16(a1[0], *(short8*)&B[cur][3], acc1[3], 0, 0, 0);
        acc0[0] = __builtin_amdgcn_mfma_f32_16x16x32_bf16(a0[1], *(short8*)&B[cur][4], acc0[0], 0, 0, 0);
        acc0[1] = __builtin_amdgcn_mfma_f32_16x16x32_bf16(a0[1], *(short8*)&B[cur][5], acc0[1], 0, 0, 0);
        acc0[2] = __builtin_amdgcn_mfma_f32_16x16x32_bf16(a0[1], *(short8*)&B[cur][6], acc0[2], 0, 0, 0);
        acc0[3] = __builtin_amdgcn_mfma_f32_16x16x32_bf16(a0[1], *(short8*)&B[cur][7], acc0[3], 0, 0, 0);
        acc1[0] = __builtin_amdgcn_mfma_f32_16x16x32_bf16(a1[1], *(short8*)&B[cur][4], acc1[0], 0, 0, 0);
        acc1[1] = __builtin_amdgcn_mfma_f32_16x16x32_bf16(a1[1], *(short8*)&B[cur][5], acc1[1], 0, 0, 0);
        acc1[2] = __builtin_amdgcn_mfma_f32_16x16x32_bf16(a1[1], *(short8*)&B[cur][6], acc1[2], 0, 0, 0);
        acc1[3] = __builtin_amdgcn_mfma_f32_16x16x32_bf16(a1[1], *(short8*)&B[cur][7], acc1[3], 0, 0, 0);
    }

    // ---- bias K-chunk: waves 0..3 = {tile} x {e-half} ----
    if (wv < 4) {
        const int tile = wv >> 1, eh = wv & 1;
        const int e0 = eh * 32 + quad * 8;
        const int trow = tile * 16 + m;
        uint4 av;
        av.x = pack_bf16(wts[trow * 65 + e0 + 0], wts[trow * 65 + e0 + 1]);
        av.y = pack_bf16(wts[trow * 65 + e0 + 2], wts[trow * 65 + e0 + 3]);
        av.z = pack_bf16(wts[trow * 65 + e0 + 4], wts[trow * 65 + e0 + 5]);
        av.w = pack_bf16(wts[trow * 65 + e0 + 6], wts[trow * 65 + e0 + 7]);
        short8 a = *(short8*)&av;
        const uint4* bq = (const uint4*)img + (size_t)64 * 512;
        if (tile == 0) {
            #pragma unroll
            for (int u = 0; u < 4; ++u) {
                uint4 bv = bq[eh * 256 + u * 64 + lane];
                acc0[u] = __builtin_amdgcn_mfma_f32_16x16x32_bf16(a, *(short8*)&bv, acc0[u], 0, 0, 0);
            }
        } else {
            #pragma unroll
            for (int u = 0; u < 4; ++u) {
                uint4 bv = bq[eh * 256 + u * 64 + lane];
                acc1[u] = __builtin_amdgcn_mfma_f32_16x16x32_bf16(a, *(short8*)&bv, acc1[u], 0, 0, 0);
            }
        }
    }

    // ---- tree reduction over 8 wave-partials, both tiles in parallel ----
    // (C layout: row = quad*4+r, col = u*16+m)
    if (wv >= 4) {
        #pragma unroll
        for (int u = 0; u < 4; ++u)
            #pragma unroll
            for (int r = 0; r < 4; ++r) {
                const int idx = (quad * 4 + r) * 68 + u * 16 + m;
                ped0[wv - 4][idx] = acc0[u][r];
                ped1[wv - 4][idx] = acc1[u][r];
            }
    }
    __syncthreads();
    if (wv < 4) {
        #pragma unroll
        for (int u = 0; u < 4; ++u)
            #pragma unroll
            for (int r = 0; r < 4; ++r) {
                const int idx = (quad * 4 + r) * 68 + u * 16 + m;
                acc0[u][r] += ped0[wv][idx];
                acc1[u][r] += ped1[wv][idx];
            }
    }
    __syncthreads();
    if (wv == 2 || wv == 3) {
        #pragma unroll
        for (int u = 0; u < 4; ++u)
            #pragma unroll
            for (int r = 0; r < 4; ++r) {
                const int idx = (quad * 4 + r) * 68 + u * 16 + m;
                ped0[wv - 2][idx] = acc0[u][r];
                ped1[wv - 2][idx] = acc1[u][r];
            }
    }
    __syncthreads();
    if (wv < 2) {
        #pragma unroll
        for (int u = 0; u < 4; ++u)
            #pragma unroll
            for (int r = 0; r < 4; ++r) {
                const int idx = (quad * 4 + r) * 68 + u * 16 + m;
                acc0[u][r] += ped0[wv][idx];
                acc1[u][r] += ped1[wv][idx];
            }
    }
    __syncthreads();
    if (wv == 1) {
        #pragma unroll
        for (int u = 0; u < 4; ++u)
            #pragma unroll
            for (int r = 0; r < 4; ++r) {
                const int idx = (quad * 4 + r) * 68 + u * 16 + m;
                ped0[0][idx] = acc0[u][r];
                ped1[0][idx] = acc1[u][r];
            }
    }
    __syncthreads();
    if (wv == 0) {
        #pragma unroll
        for (int u = 0; u < 4; ++u)
            #pragma unroll
            for (int r = 0; r < 4; ++r) {
                const int idx = (quad * 4 + r) * 68 + u * 16 + m;
                ped0[0][idx] += acc0[u][r];
                ped1[0][idx] += acc1[u][r];
            }
    }
    __syncthreads();

    // ---- final store: 32 tokens x 16 float4, coalesced ----
    {
        const int t = tid >> 4, kq = tid & 15;
        const float* srcp = (t < 16) ? &ped0[0][t * 68 + kq * 4]
                                     : &ped1[0][(t - 16) * 68 + kq * 4];
        *(float4*)(out + (size_t)(tokbase + t) * 64 + kq * 4) = *(const float4*)srcp;
    }
}

// ======================================================================
// Fallback (ws-free), validated structure: 1024 blocks x 512 thr, 16 tok
// ======================================================================
__device__ __forceinline__ void gen_a_fb(const float* __restrict__ ew1,
                                         const float* __restrict__ eb1,
                                         int f, int quad, float xv, float wt,
                                         short8* a) {
    #pragma unroll
    for (int c = 0; c < 2; ++c) {
        const float* w1p = ew1 + f * 64 + c * 32 + quad * 8;
        const float* b1p = eb1 + f * 64 + c * 32 + quad * 8;
        const float4 w1a = *(const float4*)w1p, w1b = *(const float4*)(w1p + 4);
        const float4 b1a = *(const float4*)b1p, b1b = *(const float4*)(b1p + 4);
        uint4 av;
        av.x = pack_bf16(wt * eluf(fmaf(xv, w1a.x, b1a.x)),
                         wt * eluf(fmaf(xv, w1a.y, b1a.y)));
        av.y = pack_bf16(wt * eluf(fmaf(xv, w1a.z, b1a.z)),
                         wt * eluf(fmaf(xv, w1a.w, b1a.w)));
        av.z = pack_bf16(wt * eluf(fmaf(xv, w1b.x, b1b.x)),
                         wt * eluf(fmaf(xv, w1b.y, b1b.y)));
        av.w = pack_bf16(wt * eluf(fmaf(xv, w1b.z, b1b.z)),
                         wt * eluf(fmaf(xv, w1b.w, b1b.w)));
        a[c] = *(short8*)&av;
    }
}
__device__ __forceinline__ void gen_b_fp32(const float* __restrict__ w3f,
                                           int quad, int m, short8 b[2][4]) {
    #pragma unroll
    for (int c = 0; c < 2; ++c)
        #pragma unroll
        for (int u = 0; u < 4; ++u) {
            const float* wp = w3f + (size_t)(c * 32 + quad * 8) * 64 + u * 16 + m;
            uint4 v;
            v.x = pack_bf16(wp[0],   wp[64]);
            v.y = pack_bf16(wp[128], wp[192]);
            v.z = pack_bf16(wp[256], wp[320]);
            v.w = pack_bf16(wp[384], wp[448]);
            b[c][u] = *(short8*)&v;
        }
}

__global__ __launch_bounds__(512, 8)
void moe_fb(const float* __restrict__ x,   const float* __restrict__ s,
            const float* __restrict__ fw1, const float* __restrict__ fb1,
            const float* __restrict__ fw2, const float* __restrict__ fb2,
            const float* __restrict__ fw3, const float* __restrict__ fb3,
            const float* __restrict__ ew1, const float* __restrict__ eb1,
            const float* __restrict__ ew3, const float* __restrict__ eb3,
            float* __restrict__ out)
{
    __shared__ __align__(16) float xls[16 * 68];
    __shared__ __align__(16) float wts[16 * 65];
    __shared__ __align__(16) float egs[16 * 64];
    __shared__ __align__(16) float ped[4][16 * 68];

    const int tid = threadIdx.x;
    const int wv = tid >> 6, lane = tid & 63;
    const int tokbase = blockIdx.x * 16;

    if (tid < 256) {
        const int t = tid >> 4, fq = (tid & 15) * 4;
        *(float4*)&xls[t * 68 + fq] =
            *(const float4*)(x + (size_t)(tokbase + t) * 64 + fq);
    }
    __syncthreads();
    {
        const int t0w = wv * 2;
        const float* sw = s + (size_t)(tokbase + t0w) * 32;
        float g0, g1;
        g0 = g1 = fb1[lane] + fb2[lane];
        for (int ff = 0; ff < 64; ff += 4) {
            const float4 xa = *(const float4*)&xls[(t0w + 0) * 68 + ff];
            const float4 xb = *(const float4*)&xls[(t0w + 1) * 68 + ff];
            const float w0 = fw1[(ff + 0) * 64 + lane];
            const float w1 = fw1[(ff + 1) * 64 + lane];
            const float w2 = fw1[(ff + 2) * 64 + lane];
            const float w3v = fw1[(ff + 3) * 64 + lane];
            g0 = fmaf(xa.x, w0, fmaf(xa.y, w1, fmaf(xa.z, w2, fmaf(xa.w, w3v, g0))));
            g1 = fmaf(xb.x, w0, fmaf(xb.y, w1, fmaf(xb.z, w2, fmaf(xb.w, w3v, g1))));
        }
        for (int e = 0; e < 32; e += 4) {
            const float4 sa = *(const float4*)(sw + e);
            const float4 sb = *(const float4*)(sw + 32 + e);
            const float w0 = fw2[(e + 0) * 64 + lane];
            const float w1 = fw2[(e + 1) * 64 + lane];
            const float w2 = fw2[(e + 2) * 64 + lane];
            const float w3v = fw2[(e + 3) * 64 + lane];
            g0 = fmaf(sa.x, w0, fmaf(sa.y, w1, fmaf(sa.z, w2, fmaf(sa.w, w3v, g0))));
            g1 = fmaf(sb.x, w0, fmaf(sb.y, w1, fmaf(sb.z, w2, fmaf(sb.w, w3v, g1))));
        }
        egs[(t0w + 0) * 64 + lane] = eluf(g0);
        egs[(t0w + 1) * 64 + lane] = eluf(g1);
        float lg0 = fb3[lane], lg1 = lg0;
        for (int h = 0; h < 64; h += 4) {
            const float4 e0 = *(const float4*)&egs[(t0w + 0) * 64 + h];
            const float4 e1 = *(const float4*)&egs[(t0w + 1) * 64 + h];
            const float w0 = fw3[(h + 0) * 64 + lane];
            const float w1 = fw3[(h + 1) * 64 + lane];
            const float w2 = fw3[(h + 2) * 64 + lane];
            const float w3v = fw3[(h + 3) * 64 + lane];
            lg0 = fmaf(e0.x, w0, fmaf(e0.y, w1, fmaf(e0.z, w2, fmaf(e0.w, w3v, lg0))));
            lg1 = fmaf(e1.x, w0, fmaf(e1.y, w1, fmaf(e1.z, w2, fmaf(e1.w, w3v, lg1))));
        }
        float mx0 = lg0, mx1 = lg1;
        #pragma unroll
        for (int off = 32; off > 0; off >>= 1) {
            mx0 = fmaxf(mx0, __shfl_xor(mx0, off));
            mx1 = fmaxf(mx1, __shfl_xor(mx1, off));
        }
        const float p0 = __expf(lg0 - mx0), p1 = __expf(lg1 - mx1);
        float s0 = p0, s1 = p1;
        #pragma unroll
        for (int off = 32; off > 0; off >>= 1) {
            s0 += __shfl_xor(s0, off);
            s1 += __shfl_xor(s1, off);
        }
        wts[(t0w + 0) * 65 + lane] = p0 / s0;
        wts[(t0w + 1) * 65 + lane] = p1 / s1;
    }
    __syncthreads();

    const int m = tid & 15, quad = (tid >> 4) & 3;
    const int f0 = wv * 8;
    f32x4 acc[4];
    #pragma unroll
    for (int u = 0; u < 4; ++u) acc[u] = (f32x4){0.f, 0.f, 0.f, 0.f};

    #pragma unroll
    for (int ff = 0; ff < 8; ++ff) {
        const int fcur = f0 + ff;
        short8 b[2][4], a[2];
        gen_b_fp32(ew3 + (size_t)fcur * 4096, quad, m, b);
        gen_a_fb(ew1, eb1, fcur, quad, xls[m * 68 + fcur], wts[m * 65 + fcur], a);
        #pragma unroll
        for (int u = 0; u < 4; ++u) {
            acc[u] = __builtin_amdgcn_mfma_f32_16x16x32_bf16(a[0], b[0][u], acc[u], 0, 0, 0);
            acc[u] = __builtin_amdgcn_mfma_f32_16x16x32_bf16(a[1], b[1][u], acc[u], 0, 0, 0);
        }
    }
    if (wv < 2) {
        const int e0 = wv * 32 + quad * 8;
        uint4 av;
        av.x = pack_bf16(wts[m * 65 + e0 + 0], wts[m * 65 + e0 + 1]);
        av.y = pack_bf16(wts[m * 65 + e0 + 2], wts[m * 65 + e0 + 3]);
        av.z = pack_bf16(wts[m * 65 + e0 + 4], wts[m * 65 + e0 + 5]);
        av.w = pack_bf16(wts[m * 65 + e0 + 6], wts[m * 65 + e0 + 7]);
        short8 a = *(short8*)&av;
        #pragma unroll
        for (int u = 0; u < 4; ++u) {
            const float* wp = eb3 + (size_t)e0 * 64 + u * 16 + m;
            uint4 bv;
            bv.x = pack_bf16(wp[0],   wp[64]);
            bv.y = pack_bf16(wp[128], wp[192]);
            bv.z = pack_bf16(wp[256], wp[320]);
            bv.w = pack_bf16(wp[384], wp[448]);
            acc[u] = __builtin_amdgcn_mfma_f32_16x16x32_bf16(a, *(short8*)&bv, acc[u], 0, 0, 0);
        }
    }
    if (wv >= 4) {
        #pragma unroll
        for (int u = 0; u < 4; ++u)
            #pragma unroll
            for (int r = 0; r < 4; ++r)
                ped[wv - 4][(quad * 4 + r) * 68 + u * 16 + m] = acc[u][r];
    }
    __syncthreads();
    if (wv < 4) {
        #pragma unroll
        for (int u = 0; u < 4; ++u)
            #pragma unroll
            for (int r = 0; r < 4; ++r)
                acc[u][r] += ped[wv][(quad * 4 + r) * 68 + u * 16 + m];
    }
    __syncthreads();
    if (wv == 2 || wv == 3) {
        #pragma unroll
        for (int u = 0; u < 4; ++u)
            #pragma unroll
            for (int r = 0; r < 4; ++r)
                ped[wv - 2][(quad * 4 + r) * 68 + u * 16 + m] = acc[u][r];
    }
    __syncthreads();
    if (wv < 2) {
        #pragma unroll
        for (int u = 0; u < 4; ++u)
            #pragma unroll
            for (int r = 0; r < 4; ++r)
                acc[u][r] += ped[wv][(quad * 4 + r) * 68 + u * 16 + m];
    }
    __syncthreads();
    if (wv == 1) {
        #pragma unroll
        for (int u = 0; u < 4; ++u)
            #pragma unroll
            for (int r = 0; r < 4; ++r)
                ped[0][(quad * 4 + r) * 68 + u * 16 + m] = acc[u][r];
    }
    __syncthreads();
    if (wv == 0) {
        #pragma unroll
        for (int u = 0; u < 4; ++u)
            #pragma unroll
            for (int r = 0; r < 4; ++r)
                ped[0][(quad * 4 + r) * 68 + u * 16 + m] += acc[u][r];
    }
    __syncthreads();
    if (tid < 256) {
        const int t = tid >> 4, kq = tid & 15;
        float4 o = *(const float4*)&ped[0][t * 68 + kq * 4];
        *(float4*)(out + (size_t)(tokbase + t) * 64 + kq * 4) = o;
    }
}

extern "C" void kernel_launch(void* const* d_in, const int* in_sizes, int n_in,
                              void* d_out, int out_size, void* d_ws, size_t ws_size,
                              hipStream_t stream) {
    const float* x   = (const float*)d_in[0];
    const float* s   = (const float*)d_in[1];
    const float* fw1 = (const float*)d_in[2];
    const float* fb1 = (const float*)d_in[3];
    const float* fw2 = (const float*)d_in[4];
    const float* fb2 = (const float*)d_in[5];
    const float* fw3 = (const float*)d_in[6];
    const float* fb3 = (const float*)d_in[7];
    const float* ew1 = (const float*)d_in[8];
    const float* eb1 = (const float*)d_in[9];
    const float* ew3 = (const float*)d_in[10];
    const float* eb3 = (const float*)d_in[11];
    float* out = (float*)d_out;

    const size_t ws_need = (size_t)65 * 4096 * sizeof(unsigned short);  // 532,480 B
    if (ws_size >= ws_need && (((uintptr_t)d_ws & 15) == 0)) {
        unsigned short* img = (unsigned short*)d_ws;
        prepass<<<dim3(65), dim3(256), 0, stream>>>(ew3, eb3, img);
        moe_main<<<dim3(NTOK / 32), dim3(512), 0, stream>>>(
            x, s, fw1, fb1, fw2, fb2, fw3, fb3, ew1, eb1, ew3, eb3, img, out);
    } else {
        moe_fb<<<dim3(NTOK / 16), dim3(512), 0, stream>>>(
            x, s, fw1, fb1, fw2, fb2, fw3, fb3, ew1, eb1, ew3, eb3, out);
    }
}